// Round 11
// baseline (2567.048 us; speedup 1.0000x reference)
//
#include <hip/hip_runtime.h>

// ---------------- problem constants ----------------
#define Bn 32
#define Tn 64
#define Pn 196
#define ENCD 2048
#define DECD 512
#define XDIM 2304

typedef unsigned short u16;
typedef __attribute__((ext_vector_type(8))) short bf16x8;
typedef __attribute__((ext_vector_type(4))) float f32x4;

#define MF(a,b,c) __builtin_amdgcn_mfma_f32_16x16x32_bf16(a,b,c,0,0,0)

static __device__ __forceinline__ u16 f2bf(float f){
  unsigned int u = __float_as_uint(f);
  unsigned int r = u + 0x7FFFu + ((u >> 16) & 1u);
  return (u16)(r >> 16);
}
static __device__ __forceinline__ float bf2f(u16 u){
  return __uint_as_float(((unsigned int)u) << 16);
}

// ---------------- output offsets (floats) ----------------
#define O_PRED   0
#define O_STOP   4096
#define O_SEQOFF 6144
#define O_LEN    10240
#define O_ALPHA  10272
#define O_SORT   411680

// ---------------- ws: f32/int region (f32 indices) ----------------
#define WS_SORT    0        // int[32]
#define WS_LEN     32       // int[32]
#define WS_C       64       // f32 [32][512]
#define WS_PA      16448    // f32 [32][4608] (att2 0..511 | gateRaw 512..2559 | hh 2560..4607)
#define WS_ENCM    215104   // f32 [32][2048]
#define WS_EMB0    280640   // f32 [32][256]
#define WS_BCOMB   288832   // f32 [2048] -> ends 290,880 f32 = 1,163,520 B < 1.6 MB
// ---------------- ws: u16 region (absolute u16 indices from (u16*)d_ws) ----------------
#define US_H0      800000                 // [32][512]
#define US_H1      816384                 // [32][512]
#define US_XA      832768                 // [32][2048]
#define US_EMBBF   898304                 // [32][64][256]
#define US_ATT1T   1422592                // [32][512][208] transposed att1
#define US_ENC     4830464                // [6272][2048] sorted row-major
#define US_WAP     17675520               // [4672][512] Wdec|Wfb|Whh|Wfc(2)|Wstop|pad
#define US_WIHE    20067584               // [2048][256]  jp-interleaved
#define US_WIH2    20591872               // [2048][2048] jp-interleaved
#define US_GEMB    24786176               // [32*64][2048] -> end 28,980,480 u16 = 58.0 MB
#define US_PATCH   20591872               // [2048][3072] ALIAS over WIH2+GEMB head (pre-cvt2)
#define US_WEA     27931904               // [512][2048]  ALIAS in GEMB tail (pre-gemb)

// ============ prep: stable descending sort ============
__global__ void k_prep(const int* __restrict__ caplen, int* __restrict__ ws_sort,
                       int* __restrict__ ws_len, float* __restrict__ out){
  __shared__ int len[32];
  int i = threadIdx.x;
  if (i < 32) len[i] = caplen[i];
  __syncthreads();
  if (i < 32){
    int li = len[i], r = 0;
    for (int j = 0; j < 32; j++){
      int lj = len[j];
      r += (lj > li) || (lj == li && j < i);
    }
    ws_sort[r] = i;
    ws_len[r]  = li;
    out[O_LEN + r]  = (float)li;
    out[O_SORT + r] = (float)i;
  }
}

__global__ void k_seqoff(const float* __restrict__ seqoff, const int* __restrict__ ws_sort,
                         float* __restrict__ out){
  int idx = blockIdx.x*256 + threadIdx.x;
  int b = idx >> 7, r = idx & 127;
  out[O_SEQOFF + idx] = seqoff[ws_sort[b]*128 + r];
}

// ============ enc -> sorted row-major bf16 [6272][2048] ============
__global__ void k_encbf(const float* __restrict__ enc, const int* __restrict__ srt,
                        u16* __restrict__ dst){
  int m = blockIdx.x;
  int b = m / 196, p = m - b*196;
  const float* src = enc + ((size_t)srt[b]*196 + p)*ENCD;
  u16* d = dst + (size_t)m*ENCD;
  int i = threadIdx.x*8;
  float4 v0 = *(const float4*)(src + i);
  float4 v1 = *(const float4*)(src + i + 4);
  bf16x8 s;
  s[0]=(short)f2bf(v0.x); s[1]=(short)f2bf(v0.y); s[2]=(short)f2bf(v0.z); s[3]=(short)f2bf(v0.w);
  s[4]=(short)f2bf(v1.x); s[5]=(short)f2bf(v1.y); s[6]=(short)f2bf(v1.z); s[7]=(short)f2bf(v1.w);
  *(bf16x8*)(d + i) = s;
}

__global__ void k_encmean(const u16* __restrict__ encbf, float* __restrict__ encm){
  int b = blockIdx.x >> 3, dc = blockIdx.x & 7;
  int d = dc*256 + threadIdx.x;
  const u16* ep = encbf + (size_t)(b*196)*ENCD + d;
  float s = 0.f;
  #pragma unroll 4
  for (int p = 0; p < Pn; p++) s += bf2f(ep[(size_t)p*ENCD]);
  encm[b*ENCD + d] = s * (1.f/196.f);
}

// ============ patch extraction -> bf16 ============
__global__ void k_patch(const float* __restrict__ imgs, const int* __restrict__ seq,
                        const int* __restrict__ srt, u16* __restrict__ patches){
  int blk = blockIdx.x; int b = blk>>6, t = blk&63;
  int sb = srt[b];
  int x0 = seq[(sb*64+t)*2 + 0], y0 = seq[(sb*64+t)*2 + 1];
  const float* img = imgs + (size_t)sb*3*512*512;
  u16* dst = patches + (size_t)(b*64+t)*3072;
  for (int idx = threadIdx.x; idx < 3072; idx += 256){
    int c = idx>>10, rem = idx&1023, i = rem>>5, j = rem&31;
    int yy = y0 + i - 24, xx = x0 + j - 24;
    float v = 0.f;
    if ((unsigned)yy < 512u && (unsigned)xx < 512u) v = img[((size_t)c*512 + yy)*512 + xx];
    dst[idx] = f2bf(v);
  }
}

// ============ embed GEMM ============
__global__ __launch_bounds__(256) void k_embedv2(const u16* __restrict__ patches,
    const float* __restrict__ W_pe, const float* __restrict__ b_pe,
    u16* __restrict__ embbf, float* __restrict__ emb0){
  int b = blockIdx.x >> 2, nq = blockIdx.x & 3;
  __shared__ u16 A[64*264];
  int tid = threadIdx.x, wv = tid>>6, lane = tid&63, lr = lane&15, lh = lane>>4;
  int n0 = (nq*4 + wv)*16;
  f32x4 acc[4];
  #pragma unroll
  for (int mt = 0; mt < 4; mt++) acc[mt] = (f32x4){0,0,0,0};
  for (int kc = 0; kc < 12; kc++){
    __syncthreads();
    {
      int row = tid>>2, seg = tid&3;
      const u16* src = patches + (size_t)(b*64 + row)*3072 + kc*256 + seg*64;
      #pragma unroll
      for (int i = 0; i < 8; i++)
        *(bf16x8*)&A[row*264 + seg*64 + i*8] = *(const bf16x8*)(src + i*8);
    }
    __syncthreads();
    #pragma unroll
    for (int ki = 0; ki < 8; ki++){
      const float* wp = W_pe + (size_t)(n0+lr)*3072 + kc*256 + ki*32 + lh*8;
      float4 f0 = *(const float4*)wp, f1 = *(const float4*)(wp + 4);
      bf16x8 bv;
      bv[0]=(short)f2bf(f0.x); bv[1]=(short)f2bf(f0.y); bv[2]=(short)f2bf(f0.z); bv[3]=(short)f2bf(f0.w);
      bv[4]=(short)f2bf(f1.x); bv[5]=(short)f2bf(f1.y); bv[6]=(short)f2bf(f1.z); bv[7]=(short)f2bf(f1.w);
      #pragma unroll
      for (int mt = 0; mt < 4; mt++){
        bf16x8 av = *(const bf16x8*)&A[(mt*16 + lr)*264 + ki*32 + lh*8];
        acc[mt] = MF(av, bv, acc[mt]);
      }
    }
  }
  float bias = b_pe[n0 + lr];
  #pragma unroll
  for (int mt = 0; mt < 4; mt++){
    #pragma unroll
    for (int r = 0; r < 4; r++){
      int ml = mt*16 + lh*4 + r;
      float val = acc[mt][r] + bias;
      embbf[(size_t)(b*64 + ml)*256 + n0 + lr] = f2bf(val);
      if (ml == 0) emb0[b*256 + n0 + lr] = val;
    }
  }
}

// ============ weight converts ============
__global__ void k_cvt2(const float* __restrict__ Wih, const float* __restrict__ Whh,
    const float* __restrict__ Wdec, const float* __restrict__ Wfb,
    const float* __restrict__ Wfc, const float* __restrict__ Wstop,
    const float* __restrict__ Wea, const float* __restrict__ bih, const float* __restrict__ bhh,
    u16* __restrict__ WIH2, u16* __restrict__ WIHE,
    u16* __restrict__ WAP, u16* __restrict__ WEAd, float* __restrict__ bcomb){
  int blk = blockIdx.x, tid = threadIdx.x;
  if (blk < 2048){
    int r = blk, jp = (r & 511)*4 + (r >> 9);
    for (int i = tid; i < 2304; i += 256){
      u16 v = f2bf(Wih[(size_t)r*2304 + i]);
      if (i < 2048) WIH2[(size_t)jp*2048 + i] = v;
      else          WIHE[(size_t)jp*256 + (i - 2048)] = v;
    }
  } else if (blk < 6720){
    int j = blk - 2048;
    const float* src;
    if (j < 512)        src = Wdec + (size_t)j*512;
    else if (j < 2560)  src = Wfb + (size_t)(j-512)*512;
    else if (j < 4608)  src = Whh + (size_t)(j-2560)*512;
    else if (j == 4608) src = Wfc;
    else if (j == 4609) src = Wfc + 512;
    else if (j == 4610) src = Wstop;
    else src = 0;
    for (int i = tid; i < 512; i += 256)
      WAP[(size_t)j*512 + i] = src ? f2bf(src[i]) : (u16)0;
  } else if (blk < 7232){
    int r = blk - 6720;
    for (int i = tid; i < 2048; i += 256)
      WEAd[(size_t)r*2048 + i] = f2bf(Wea[(size_t)r*2048 + i]);
  } else {
    int jp = (blk - 7232)*256 + tid;
    int r = (jp & 3)*512 + (jp >> 2);
    bcomb[jp] = bih[r] + bhh[r];
  }
}

// ============ G_emb = emb @ WIHE^T ============
__global__ __launch_bounds__(256) void k_gemb(const u16* __restrict__ embbf,
    const u16* __restrict__ WIHE, u16* __restrict__ gemb){
  int m0 = (blockIdx.x >> 3)*64, n0 = (blockIdx.x & 7)*256;
  __shared__ u16 A[64*264];
  int tid = threadIdx.x, wv = tid>>6, lane = tid&63, lr = lane&15, lh = lane>>4;
  {
    int row = tid>>2, seg = tid&3;
    const u16* src = embbf + (size_t)(m0 + row)*256 + seg*64;
    #pragma unroll
    for (int i = 0; i < 8; i++)
      *(bf16x8*)&A[row*264 + seg*64 + i*8] = *(const bf16x8*)(src + i*8);
  }
  __syncthreads();
  f32x4 acc[4][4];
  #pragma unroll
  for (int mt = 0; mt < 4; mt++)
    #pragma unroll
    for (int nt = 0; nt < 4; nt++) acc[mt][nt] = (f32x4){0,0,0,0};
  #pragma unroll
  for (int ki = 0; ki < 8; ki++){
    bf16x8 av[4];
    #pragma unroll
    for (int mt = 0; mt < 4; mt++)
      av[mt] = *(const bf16x8*)&A[(mt*16 + lr)*264 + ki*32 + lh*8];
    #pragma unroll
    for (int nt = 0; nt < 4; nt++){
      bf16x8 bv = *(const bf16x8*)&WIHE[(size_t)(n0 + wv*64 + nt*16 + lr)*256 + ki*32 + lh*8];
      #pragma unroll
      for (int mt = 0; mt < 4; mt++) acc[mt][nt] = MF(av[mt], bv, acc[mt][nt]);
    }
  }
  #pragma unroll
  for (int nt = 0; nt < 4; nt++){
    int n = n0 + wv*64 + nt*16 + lr;
    #pragma unroll
    for (int mt = 0; mt < 4; mt++)
      #pragma unroll
      for (int r = 0; r < 4; r++)
        gemb[(size_t)(m0 + mt*16 + lh*4 + r)*2048 + n] = f2bf(acc[mt][nt][r]);
  }
}

// ============ att1 v4 (bf16 source, N-split 4) -> TRANSPOSED att1T[b][512][208] ============
__global__ __launch_bounds__(256) void k_att1v4(const u16* __restrict__ encbf,
    const u16* __restrict__ Wea, const float* __restrict__ bea, u16* __restrict__ att1T){
  int mb = blockIdx.x >> 2, nb = blockIdx.x & 3;
  int m0 = mb*64;
  __shared__ u16 A[64*136];
  int tid = threadIdx.x, wv = tid>>6, lane = tid&63, lr = lane&15, lh = lane>>4;
  f32x4 acc[4][2];
  #pragma unroll
  for (int mt = 0; mt < 4; mt++){ acc[mt][0] = (f32x4){0,0,0,0}; acc[mt][1] = (f32x4){0,0,0,0}; }
  for (int kc = 0; kc < 16; kc++){
    __syncthreads();
    {
      int row = tid>>2, seg = tid&3;
      const u16* src = encbf + (size_t)(m0 + row)*2048 + kc*128 + seg*32;
      #pragma unroll
      for (int i = 0; i < 4; i++)
        *(bf16x8*)&A[row*136 + seg*32 + i*8] = *(const bf16x8*)(src + i*8);
    }
    __syncthreads();
    #pragma unroll
    for (int ki = 0; ki < 4; ki++){
      bf16x8 av[4];
      #pragma unroll
      for (int mt = 0; mt < 4; mt++)
        av[mt] = *(const bf16x8*)&A[(mt*16 + lr)*136 + ki*32 + lh*8];
      #pragma unroll
      for (int nt = 0; nt < 2; nt++){
        const u16* wp = Wea + (size_t)(nb*128 + wv*32 + nt*16 + lr)*2048 + kc*128 + ki*32 + lh*8;
        bf16x8 bv = *(const bf16x8*)wp;
        #pragma unroll
        for (int mt = 0; mt < 4; mt++) acc[mt][nt] = MF(av[mt], bv, acc[mt][nt]);
      }
    }
  }
  #pragma unroll
  for (int nt = 0; nt < 2; nt++){
    int n = nb*128 + wv*32 + nt*16 + lr;
    float bias = bea[n];
    #pragma unroll
    for (int mt = 0; mt < 4; mt++){
      #pragma unroll
      for (int r = 0; r < 4; r++){
        int m = m0 + mt*16 + lh*4 + r;
        int bb = m / 196, pp = m - bb*196;
        att1T[((size_t)bb*512 + n)*208 + pp] = f2bf(acc[mt][nt][r] + bias);
      }
    }
  }
}

// ============ h,c init ============
__global__ __launch_bounds__(256) void k_init(const float* __restrict__ encm, const float* __restrict__ emb0,
    const float* __restrict__ Wh, const float* __restrict__ bh,
    const float* __restrict__ Wc, const float* __restrict__ bc,
    u16* __restrict__ h_bf, float* __restrict__ c){
  int mat = blockIdx.x >> 4, jb = blockIdx.x & 15;
  const float* W    = mat ? Wc : Wh;
  const float* bias = mat ? bc : bh;
  int j0 = jb*32;
  __shared__ float XT[256*36];
  int bq = threadIdx.x & 7, jq = threadIdx.x >> 3;
  float acc[4] = {0.f,0.f,0.f,0.f};
  for (int ch = 0; ch < 9; ch++){
    int k0 = ch*256;
    __syncthreads();
    {
      int m = threadIdx.x >> 3, kq8 = threadIdx.x & 7;
      #pragma unroll
      for (int i = 0; i < 8; i++){
        int kq = kq8 + i*8;
        int k = k0 + kq*4;
        float4 v;
        if (k < 2048) v = *(const float4*)&encm[m*ENCD + k];
        else          v = *(const float4*)&emb0[m*256 + (k - 2048)];
        XT[(4*kq+0)*36+m]=v.x; XT[(4*kq+1)*36+m]=v.y; XT[(4*kq+2)*36+m]=v.z; XT[(4*kq+3)*36+m]=v.w;
      }
    }
    __syncthreads();
    int j = j0 + jq;
    const float* wr = W + (size_t)j*XDIM + k0;
    #pragma unroll 2
    for (int k4 = 0; k4 < 64; k4++){
      float4 wv = *(const float4*)(wr + k4*4);
      float4 x0 = *(float4*)&XT[(k4*4+0)*36 + bq*4];
      float4 x1 = *(float4*)&XT[(k4*4+1)*36 + bq*4];
      float4 x2 = *(float4*)&XT[(k4*4+2)*36 + bq*4];
      float4 x3 = *(float4*)&XT[(k4*4+3)*36 + bq*4];
      acc[0] += x0.x*wv.x + x1.x*wv.y + x2.x*wv.z + x3.x*wv.w;
      acc[1] += x0.y*wv.x + x1.y*wv.y + x2.y*wv.z + x3.y*wv.w;
      acc[2] += x0.z*wv.x + x1.z*wv.y + x2.z*wv.z + x3.z*wv.w;
      acc[3] += x0.w*wv.x + x1.w*wv.y + x2.w*wv.z + x3.w*wv.w;
    }
  }
  #pragma unroll
  for (int bb = 0; bb < 4; bb++){
    float v = acc[bb] + bias[j0 + jq];
    int row = bq*4 + bb;
    if (mat == 0) h_bf[row*DECD + j0 + jq] = f2bf(v);
    else          c[row*DECD + j0 + jq] = v;
  }
}

// ============ kA: pA = h @ [Wdec|Wfb|Whh]^T ; preds/stop(t-1) ============
__global__ __launch_bounds__(256) void kA(const u16* __restrict__ h, const u16* __restrict__ WAP,
    float* __restrict__ pA, const float* __restrict__ bfc, const float* __restrict__ bstop,
    const int* __restrict__ len, float* __restrict__ out, int t){
  if (t == 64 && blockIdx.x != 72) return;   // final call: only preds block needed
  __shared__ u16 HL[32*520];
  int tid = threadIdx.x, wv = tid>>6, lane = tid&63, lr = lane&15, lh = lane>>4;
  for (int i = tid; i < 4096; i += 256){
    unsigned long long v = ((const unsigned long long*)h)[i];
    int row = i >> 7, col = (i & 127)*4;
    *(unsigned long long*)&HL[row*520 + col] = v;
  }
  __syncthreads();
  int j0 = blockIdx.x*64 + wv*16;
  f32x4 acc0 = {0,0,0,0}, acc1 = {0,0,0,0};
  #pragma unroll 4
  for (int ki = 0; ki < 16; ++ki){
    bf16x8 bv = *(const bf16x8*)&WAP[(size_t)(j0+lr)*512 + ki*32 + lh*8];
    bf16x8 a0 = *(const bf16x8*)&HL[lr*520 + ki*32 + lh*8];
    bf16x8 a1 = *(const bf16x8*)&HL[(16+lr)*520 + ki*32 + lh*8];
    acc0 = MF(a0, bv, acc0);
    acc1 = MF(a1, bv, acc1);
  }
  int j = j0 + lr;
  if (j < 4608){
    #pragma unroll
    for (int r = 0; r < 4; ++r){
      pA[(size_t)(lh*4+r)*4608 + j]    = acc0[r];
      pA[(size_t)(lh*4+r+16)*4608 + j] = acc1[r];
    }
  } else if (j < 4611 && t > 0){
    int jj = j - 4608, tm1 = t - 1;
    #pragma unroll
    for (int r = 0; r < 4; ++r){
      #pragma unroll
      for (int hb = 0; hb < 2; ++hb){
        int b0 = lh*4 + r + hb*16;
        float val = hb ? acc1[r] : acc0[r];
        bool mk = tm1 < len[b0];
        if (jj < 2) out[O_PRED + ((size_t)b0*64 + tm1)*2 + jj] = mk ? val + bfc[jj] : 0.f;
        else        out[O_STOP + (size_t)b0*64 + tm1] =
                      mk ? 1.f/(1.f + expf(-(val + bstop[0]))) : 0.f;
      }
    }
  }
}

// ============ kB: scores + softmax + awe + gate -> xa ; alphas ============
// grid 128 = 4 dc(512 d) x 32 b, blk = dc*32 + b (same-b blocks share an XCD)
__global__ __launch_bounds__(512) void kB(const float* __restrict__ pA,
    const u16* __restrict__ att1T, const u16* __restrict__ encbf,
    const float* __restrict__ bdec, const float* __restrict__ wfull,
    const float* __restrict__ bfull, const float* __restrict__ bfb,
    u16* __restrict__ xa, const int* __restrict__ len, float* __restrict__ out, int t){
  int dc = blockIdx.x >> 5, b = blockIdx.x & 31;
  int tid = threadIdx.x, wv = tid>>6, lane = tid&63;
  if (t >= len[b]){
    if (dc == 0 && tid < 196) out[O_ALPHA + ((size_t)b*64 + t)*196 + tid] = 0.f;
    return;
  }
  __shared__ float a2[512], wf[512];
  __shared__ float psc[2][200];
  __shared__ float ev[200], redf[8], bcx[2];
  a2[tid] = pA[(size_t)b*4608 + tid] + bdec[tid];
  wf[tid] = wfull[tid];
  __syncthreads();
  // score partials: waves 0-3 cover a-chunks 0-3 (hf=0), waves 4-7 chunks 4-7 (hf=1);
  // p coalesced across lanes; 4 independent fma chains per thread
  {
    int hf = tid >> 8, p = tid & 255;
    if (p < 196){
      const u16* base = att1T + ((size_t)b*512 + hf*256)*208 + p;
      const float* ap = a2 + hf*256;
      const float* wp = wf + hf*256;
      float acc[4] = {0.f,0.f,0.f,0.f};
      #pragma unroll 4
      for (int a = 0; a < 64; ++a){
        #pragma unroll
        for (int q = 0; q < 4; ++q)
          acc[q] += fmaxf(bf2f(base[(size_t)(q*64 + a)*208]) + ap[q*64 + a], 0.f) * wp[q*64 + a];
      }
      psc[hf][p] = (acc[0]+acc[1]) + (acc[2]+acc[3]);
    }
  }
  __syncthreads();
  float s = (tid < 196) ? (bfull[0] + psc[0][tid] + psc[1][tid]) : -1e30f;
  float m = s;
  #pragma unroll
  for (int o = 32; o; o >>= 1) m = fmaxf(m, __shfl_down(m, o));
  if (lane == 0) redf[wv] = m;
  __syncthreads();
  if (tid == 0){
    float mm = redf[0];
    #pragma unroll
    for (int i = 1; i < 8; ++i) mm = fmaxf(mm, redf[i]);
    bcx[0] = mm;
  }
  __syncthreads();
  float e = (tid < 196) ? expf(s - bcx[0]) : 0.f;
  if (tid < 200) ev[tid] = (tid < 196) ? e : 0.f;
  float sm = e;
  #pragma unroll
  for (int o = 32; o; o >>= 1) sm += __shfl_down(sm, o);
  __syncthreads();
  if (lane == 0) redf[wv] = sm;
  __syncthreads();
  if (tid == 0){
    float ss = 0.f;
    #pragma unroll
    for (int i = 0; i < 8; ++i) ss += redf[i];
    bcx[1] = ss;
  }
  __syncthreads();
  float ssum = bcx[1];
  // awe for d-chunk dc (512 d), 8 independent chains
  int d = dc*512 + tid;
  const u16* ep = encbf + (size_t)(b*196)*ENCD + d;
  float q[8];
  #pragma unroll
  for (int j = 0; j < 8; ++j) q[j] = 0.f;
  #pragma unroll 2
  for (int p = 0; p < 192; p += 8){
    #pragma unroll
    for (int j = 0; j < 8; ++j)
      q[j] += ev[p+j]*bf2f(ep[(size_t)(p+j)*ENCD]);
  }
  #pragma unroll
  for (int j = 0; j < 4; ++j)
    q[j] += ev[192+j]*bf2f(ep[(size_t)(192+j)*ENCD]);
  float awe = (((q[0]+q[1])+(q[2]+q[3])) + ((q[4]+q[5])+(q[6]+q[7]))) / ssum;
  float gp = pA[(size_t)b*4608 + 512 + d] + bfb[d];
  float gate = 1.f/(1.f + expf(-gp));
  xa[(size_t)b*2048 + d] = f2bf(gate * awe);
  if (dc == 0 && tid < 196) out[O_ALPHA + ((size_t)b*64 + t)*196 + tid] = ev[tid]/ssum;
}

// ============ kC: gates GEMM (8-wave K-split) + LSTM fused ============
__global__ __launch_bounds__(512) void kC(const u16* __restrict__ xa,
    const u16* __restrict__ hc, u16* __restrict__ hn, float* __restrict__ c,
    const u16* __restrict__ WIH2, const float* __restrict__ pA,
    const float* __restrict__ bcomb, const u16* __restrict__ gemb,
    const int* __restrict__ len, int t){
  int tid = threadIdx.x, wv = tid>>6, lane = tid&63, lr = lane&15, lh = lane>>4;
  int jp0 = blockIdx.x*16;
  __shared__ float red[8*512];
  f32x4 acc0 = {0,0,0,0}, acc1 = {0,0,0,0};
  #pragma unroll
  for (int ks = 0; ks < 8; ++ks){
    int k = wv*256 + ks*32;
    bf16x8 a0 = *(const bf16x8*)&xa[(size_t)lr*2048 + k + lh*8];
    bf16x8 a1 = *(const bf16x8*)&xa[(size_t)(16+lr)*2048 + k + lh*8];
    bf16x8 bv = *(const bf16x8*)&WIH2[(size_t)(jp0+lr)*2048 + k + lh*8];
    acc0 = MF(a0, bv, acc0);
    acc1 = MF(a1, bv, acc1);
  }
  #pragma unroll
  for (int r = 0; r < 4; ++r){
    red[wv*512 + ((lh*4+r) << 4) + lr]    = acc0[r];
    red[wv*512 + ((16+lh*4+r) << 4) + lr] = acc1[r];
  }
  __syncthreads();
  {
    int b = tid >> 4, jl = tid & 15, e = jl & 3;
    int jp = jp0 + jl, u = jp >> 2;
    float g = 0.f;
    #pragma unroll
    for (int w = 0; w < 8; ++w) g += red[w*512 + tid];
    g += bcomb[jp] + bf2f(gemb[((size_t)b*64 + t)*2048 + jp])
       + pA[(size_t)b*4608 + 2560 + e*512 + u];
    float sv = (e == 2) ? tanhf(g) : 1.f/(1.f + expf(-g));
    float vb = __shfl_xor(sv, 1), vc = __shfl_xor(sv, 2), vd = __shfl_xor(vb, 2);
    float i_s = (e==0)?sv:(e==1)?vb:(e==2)?vc:vd;
    float f_s = (e==1)?sv:(e==0)?vb:(e==3)?vc:vd;
    float g_t = (e==2)?sv:(e==3)?vb:(e==0)?vc:vd;
    float o_s = (e==3)?sv:(e==2)?vb:(e==1)?vc:vd;
    float cold = c[(size_t)b*512 + u];
    float hold = bf2f(hc[(size_t)b*512 + u]);
    bool mk = t < len[b];
    float cn = mk ? (f_s*cold + i_s*g_t) : cold;
    float hv = mk ? (o_s * tanhf(cn)) : hold;
    if (e == 0){
      c[(size_t)b*512 + u] = cn;
      hn[(size_t)b*512 + u] = f2bf(hv);
    }
  }
}

// ================= host launcher =================
extern "C" void kernel_launch(void* const* d_in, const int* in_sizes, int n_in,
                              void* d_out, int out_size, void* d_ws, size_t ws_size,
                              hipStream_t stream){
  (void)in_sizes; (void)n_in; (void)out_size; (void)ws_size;
  const float* enc_out   = (const float*)d_in[0];
  const float* imgs      = (const float*)d_in[1];
  const int*   seq       = (const int*)d_in[2];
  const float* seqoff    = (const float*)d_in[3];
  const int*   caplen    = (const int*)d_in[4];
  const float* W_pe      = (const float*)d_in[5];
  const float* b_pe      = (const float*)d_in[6];
  const float* W_enc_att = (const float*)d_in[7];
  const float* b_enc_att = (const float*)d_in[8];
  const float* W_dec_att = (const float*)d_in[9];
  const float* b_dec_att = (const float*)d_in[10];
  const float* w_full    = (const float*)d_in[11];
  const float* b_full    = (const float*)d_in[12];
  const float* W_init_h  = (const float*)d_in[13];
  const float* b_init_h  = (const float*)d_in[14];
  const float* W_init_c  = (const float*)d_in[15];
  const float* b_init_c  = (const float*)d_in[16];
  const float* W_fb      = (const float*)d_in[17];
  const float* b_fb      = (const float*)d_in[18];
  const float* W_ih      = (const float*)d_in[19];
  const float* b_ih      = (const float*)d_in[20];
  const float* W_hh      = (const float*)d_in[21];
  const float* b_hh      = (const float*)d_in[22];
  const float* W_fc      = (const float*)d_in[23];
  const float* b_fc      = (const float*)d_in[24];
  const float* W_stop    = (const float*)d_in[25];
  const float* b_stop    = (const float*)d_in[26];

  float* out = (float*)d_out;
  float* ws  = (float*)d_ws;
  int*   wsi = (int*)d_ws;
  u16*   us  = (u16*)d_ws;

  u16* H[2] = { us + US_H0, us + US_H1 };

  k_prep<<<1, 64, 0, stream>>>(caplen, wsi + WS_SORT, wsi + WS_LEN, out);
  k_seqoff<<<16, 256, 0, stream>>>(seqoff, wsi + WS_SORT, out);
  k_encbf<<<6272, 256, 0, stream>>>(enc_out, wsi + WS_SORT, us + US_ENC);
  k_encmean<<<256, 256, 0, stream>>>(us + US_ENC, ws + WS_ENCM);
  k_patch<<<2048, 256, 0, stream>>>(imgs, seq, wsi + WS_SORT, us + US_PATCH);
  k_embedv2<<<128, 256, 0, stream>>>(us + US_PATCH, W_pe, b_pe, us + US_EMBBF, ws + WS_EMB0);
  k_cvt2<<<7240, 256, 0, stream>>>(W_ih, W_hh, W_dec_att, W_fb, W_fc, W_stop, W_enc_att,
                                   b_ih, b_hh,
                                   us + US_WIH2, us + US_WIHE, us + US_WAP,
                                   us + US_WEA, ws + WS_BCOMB);
  k_att1v4<<<392, 256, 0, stream>>>(us + US_ENC, us + US_WEA, b_enc_att, us + US_ATT1T);
  k_gemb<<<256, 256, 0, stream>>>(us + US_EMBBF, us + US_WIHE, us + US_GEMB);
  k_init<<<32, 256, 0, stream>>>(ws + WS_ENCM, ws + WS_EMB0, W_init_h, b_init_h,
                                 W_init_c, b_init_c, H[0], ws + WS_C);

  for (int t = 0; t < Tn; ++t){
    kA<<<73, 256, 0, stream>>>(H[t & 1], us + US_WAP, ws + WS_PA, b_fc, b_stop,
                               wsi + WS_LEN, out, t);
    kB<<<128, 512, 0, stream>>>(ws + WS_PA, us + US_ATT1T, us + US_ENC,
                                b_dec_att, w_full, b_full, b_fb,
                                us + US_XA, wsi + WS_LEN, out, t);
    kC<<<128, 512, 0, stream>>>(us + US_XA, H[t & 1], H[(t + 1) & 1], ws + WS_C,
                                us + US_WIH2, ws + WS_PA, ws + WS_BCOMB, us + US_GEMB,
                                wsi + WS_LEN, t);
  }
  kA<<<73, 256, 0, stream>>>(H[0], us + US_WAP, ws + WS_PA, b_fc, b_stop,
                             wsi + WS_LEN, out, 64);
}

// Round 12
// 2009.675 us; speedup vs baseline: 1.2773x; 1.2773x over previous
//
#include <hip/hip_runtime.h>

// ---------------- problem constants ----------------
#define Bn 32
#define Tn 64
#define Pn 196
#define ENCD 2048
#define DECD 512
#define XDIM 2304

typedef unsigned short u16;
typedef __attribute__((ext_vector_type(8))) short bf16x8;
typedef __attribute__((ext_vector_type(4))) float f32x4;

#define MF(a,b,c) __builtin_amdgcn_mfma_f32_16x16x32_bf16(a,b,c,0,0,0)

static __device__ __forceinline__ u16 f2bf(float f){
  unsigned int u = __float_as_uint(f);
  unsigned int r = u + 0x7FFFu + ((u >> 16) & 1u);
  return (u16)(r >> 16);
}
static __device__ __forceinline__ float bf2f(u16 u){
  return __uint_as_float(((unsigned int)u) << 16);
}

// ---------------- output offsets (floats) ----------------
#define O_PRED   0
#define O_STOP   4096
#define O_SEQOFF 6144
#define O_LEN    10240
#define O_ALPHA  10272
#define O_SORT   411680

// ---------------- ws: f32/int region (f32 indices) ----------------
#define WS_SORT    0        // int[32]
#define WS_LEN     32       // int[32]
#define WS_C       64       // f32 [32][512]
#define WS_PA      16448    // f32 [32][4608] (unused 0..511 | gateRaw 512..2559 | hh 2560..4607)
#define WS_SCP     163904   // f32 [32][8][200] score partials
#define WS_ENCM    215104   // f32 [32][2048]
#define WS_EMB0    280640   // f32 [32][256]
#define WS_BCOMB   288832   // f32 [2048]
// ---------------- ws: u16 region (absolute u16 indices from (u16*)d_ws) ----------------
#define US_H0      800000                 // [32][512]
#define US_H1      816384                 // [32][512]
#define US_XA      832768                 // [32][2048]
#define US_EMBBF   898304                 // [32][64][256]
#define US_ATT1T   1422592                // [32][512][208] transposed att1
#define US_ENC     4830464                // [6272][2048] sorted row-major
#define US_WAP     17675520               // [4672][512] Wdec|Wfb|Whh|Wfc(2)|Wstop|pad
#define US_WIHE    20067584               // [2048][256]  jp-interleaved
#define US_WIH2    20591872               // [2048][2048] jp-interleaved
#define US_GEMB    24786176               // [32*64][2048]
#define US_PATCH   20591872               // [2048][3072] ALIAS over WIH2+GEMB head (pre-cvt2)
#define US_WEA     27931904               // [512][2048]  ALIAS in GEMB tail (pre-gemb)

// ============ prep: stable descending sort ============
__global__ void k_prep(const int* __restrict__ caplen, int* __restrict__ ws_sort,
                       int* __restrict__ ws_len, float* __restrict__ out){
  __shared__ int len[32];
  int i = threadIdx.x;
  if (i < 32) len[i] = caplen[i];
  __syncthreads();
  if (i < 32){
    int li = len[i], r = 0;
    for (int j = 0; j < 32; j++){
      int lj = len[j];
      r += (lj > li) || (lj == li && j < i);
    }
    ws_sort[r] = i;
    ws_len[r]  = li;
    out[O_LEN + r]  = (float)li;
    out[O_SORT + r] = (float)i;
  }
}

__global__ void k_seqoff(const float* __restrict__ seqoff, const int* __restrict__ ws_sort,
                         float* __restrict__ out){
  int idx = blockIdx.x*256 + threadIdx.x;
  int b = idx >> 7, r = idx & 127;
  out[O_SEQOFF + idx] = seqoff[ws_sort[b]*128 + r];
}

// ============ enc -> sorted row-major bf16 [6272][2048] ============
__global__ void k_encbf(const float* __restrict__ enc, const int* __restrict__ srt,
                        u16* __restrict__ dst){
  int m = blockIdx.x;
  int b = m / 196, p = m - b*196;
  const float* src = enc + ((size_t)srt[b]*196 + p)*ENCD;
  u16* d = dst + (size_t)m*ENCD;
  int i = threadIdx.x*8;
  float4 v0 = *(const float4*)(src + i);
  float4 v1 = *(const float4*)(src + i + 4);
  bf16x8 s;
  s[0]=(short)f2bf(v0.x); s[1]=(short)f2bf(v0.y); s[2]=(short)f2bf(v0.z); s[3]=(short)f2bf(v0.w);
  s[4]=(short)f2bf(v1.x); s[5]=(short)f2bf(v1.y); s[6]=(short)f2bf(v1.z); s[7]=(short)f2bf(v1.w);
  *(bf16x8*)(d + i) = s;
}

__global__ void k_encmean(const u16* __restrict__ encbf, float* __restrict__ encm){
  int b = blockIdx.x >> 3, dc = blockIdx.x & 7;
  int d = dc*256 + threadIdx.x;
  const u16* ep = encbf + (size_t)(b*196)*ENCD + d;
  float s = 0.f;
  #pragma unroll 4
  for (int p = 0; p < Pn; p++) s += bf2f(ep[(size_t)p*ENCD]);
  encm[b*ENCD + d] = s * (1.f/196.f);
}

// ============ patch extraction -> bf16 ============
__global__ void k_patch(const float* __restrict__ imgs, const int* __restrict__ seq,
                        const int* __restrict__ srt, u16* __restrict__ patches){
  int blk = blockIdx.x; int b = blk>>6, t = blk&63;
  int sb = srt[b];
  int x0 = seq[(sb*64+t)*2 + 0], y0 = seq[(sb*64+t)*2 + 1];
  const float* img = imgs + (size_t)sb*3*512*512;
  u16* dst = patches + (size_t)(b*64+t)*3072;
  for (int idx = threadIdx.x; idx < 3072; idx += 256){
    int c = idx>>10, rem = idx&1023, i = rem>>5, j = rem&31;
    int yy = y0 + i - 24, xx = x0 + j - 24;
    float v = 0.f;
    if ((unsigned)yy < 512u && (unsigned)xx < 512u) v = img[((size_t)c*512 + yy)*512 + xx];
    dst[idx] = f2bf(v);
  }
}

// ============ embed GEMM ============
__global__ __launch_bounds__(256) void k_embedv2(const u16* __restrict__ patches,
    const float* __restrict__ W_pe, const float* __restrict__ b_pe,
    u16* __restrict__ embbf, float* __restrict__ emb0){
  int b = blockIdx.x >> 2, nq = blockIdx.x & 3;
  __shared__ u16 A[64*264];
  int tid = threadIdx.x, wv = tid>>6, lane = tid&63, lr = lane&15, lh = lane>>4;
  int n0 = (nq*4 + wv)*16;
  f32x4 acc[4];
  #pragma unroll
  for (int mt = 0; mt < 4; mt++) acc[mt] = (f32x4){0,0,0,0};
  for (int kc = 0; kc < 12; kc++){
    __syncthreads();
    {
      int row = tid>>2, seg = tid&3;
      const u16* src = patches + (size_t)(b*64 + row)*3072 + kc*256 + seg*64;
      #pragma unroll
      for (int i = 0; i < 8; i++)
        *(bf16x8*)&A[row*264 + seg*64 + i*8] = *(const bf16x8*)(src + i*8);
    }
    __syncthreads();
    #pragma unroll
    for (int ki = 0; ki < 8; ki++){
      const float* wp = W_pe + (size_t)(n0+lr)*3072 + kc*256 + ki*32 + lh*8;
      float4 f0 = *(const float4*)wp, f1 = *(const float4*)(wp + 4);
      bf16x8 bv;
      bv[0]=(short)f2bf(f0.x); bv[1]=(short)f2bf(f0.y); bv[2]=(short)f2bf(f0.z); bv[3]=(short)f2bf(f0.w);
      bv[4]=(short)f2bf(f1.x); bv[5]=(short)f2bf(f1.y); bv[6]=(short)f2bf(f1.z); bv[7]=(short)f2bf(f1.w);
      #pragma unroll
      for (int mt = 0; mt < 4; mt++){
        bf16x8 av = *(const bf16x8*)&A[(mt*16 + lr)*264 + ki*32 + lh*8];
        acc[mt] = MF(av, bv, acc[mt]);
      }
    }
  }
  float bias = b_pe[n0 + lr];
  #pragma unroll
  for (int mt = 0; mt < 4; mt++){
    #pragma unroll
    for (int r = 0; r < 4; r++){
      int ml = mt*16 + lh*4 + r;
      float val = acc[mt][r] + bias;
      embbf[(size_t)(b*64 + ml)*256 + n0 + lr] = f2bf(val);
      if (ml == 0) emb0[b*256 + n0 + lr] = val;
    }
  }
}

// ============ weight converts ============
__global__ void k_cvt2(const float* __restrict__ Wih, const float* __restrict__ Whh,
    const float* __restrict__ Wdec, const float* __restrict__ Wfb,
    const float* __restrict__ Wfc, const float* __restrict__ Wstop,
    const float* __restrict__ Wea, const float* __restrict__ bih, const float* __restrict__ bhh,
    u16* __restrict__ WIH2, u16* __restrict__ WIHE,
    u16* __restrict__ WAP, u16* __restrict__ WEAd, float* __restrict__ bcomb){
  int blk = blockIdx.x, tid = threadIdx.x;
  if (blk < 2048){
    int r = blk, jp = (r & 511)*4 + (r >> 9);
    for (int i = tid; i < 2304; i += 256){
      u16 v = f2bf(Wih[(size_t)r*2304 + i]);
      if (i < 2048) WIH2[(size_t)jp*2048 + i] = v;
      else          WIHE[(size_t)jp*256 + (i - 2048)] = v;
    }
  } else if (blk < 6720){
    int j = blk - 2048;
    const float* src;
    if (j < 512)        src = Wdec + (size_t)j*512;
    else if (j < 2560)  src = Wfb + (size_t)(j-512)*512;
    else if (j < 4608)  src = Whh + (size_t)(j-2560)*512;
    else if (j == 4608) src = Wfc;
    else if (j == 4609) src = Wfc + 512;
    else if (j == 4610) src = Wstop;
    else src = 0;
    for (int i = tid; i < 512; i += 256)
      WAP[(size_t)j*512 + i] = src ? f2bf(src[i]) : (u16)0;
  } else if (blk < 7232){
    int r = blk - 6720;
    for (int i = tid; i < 2048; i += 256)
      WEAd[(size_t)r*2048 + i] = f2bf(Wea[(size_t)r*2048 + i]);
  } else {
    int jp = (blk - 7232)*256 + tid;
    int r = (jp & 3)*512 + (jp >> 2);
    bcomb[jp] = bih[r] + bhh[r];
  }
}

// ============ G_emb = emb @ WIHE^T ============
__global__ __launch_bounds__(256) void k_gemb(const u16* __restrict__ embbf,
    const u16* __restrict__ WIHE, u16* __restrict__ gemb){
  int m0 = (blockIdx.x >> 3)*64, n0 = (blockIdx.x & 7)*256;
  __shared__ u16 A[64*264];
  int tid = threadIdx.x, wv = tid>>6, lane = tid&63, lr = lane&15, lh = lane>>4;
  {
    int row = tid>>2, seg = tid&3;
    const u16* src = embbf + (size_t)(m0 + row)*256 + seg*64;
    #pragma unroll
    for (int i = 0; i < 8; i++)
      *(bf16x8*)&A[row*264 + seg*64 + i*8] = *(const bf16x8*)(src + i*8);
  }
  __syncthreads();
  f32x4 acc[4][4];
  #pragma unroll
  for (int mt = 0; mt < 4; mt++)
    #pragma unroll
    for (int nt = 0; nt < 4; nt++) acc[mt][nt] = (f32x4){0,0,0,0};
  #pragma unroll
  for (int ki = 0; ki < 8; ki++){
    bf16x8 av[4];
    #pragma unroll
    for (int mt = 0; mt < 4; mt++)
      av[mt] = *(const bf16x8*)&A[(mt*16 + lr)*264 + ki*32 + lh*8];
    #pragma unroll
    for (int nt = 0; nt < 4; nt++){
      bf16x8 bv = *(const bf16x8*)&WIHE[(size_t)(n0 + wv*64 + nt*16 + lr)*256 + ki*32 + lh*8];
      #pragma unroll
      for (int mt = 0; mt < 4; mt++) acc[mt][nt] = MF(av[mt], bv, acc[mt][nt]);
    }
  }
  #pragma unroll
  for (int nt = 0; nt < 4; nt++){
    int n = n0 + wv*64 + nt*16 + lr;
    #pragma unroll
    for (int mt = 0; mt < 4; mt++)
      #pragma unroll
      for (int r = 0; r < 4; r++)
        gemb[(size_t)(m0 + mt*16 + lh*4 + r)*2048 + n] = f2bf(acc[mt][nt][r]);
  }
}

// ============ att1 v4 (bf16 source, N-split 4) -> TRANSPOSED att1T[b][512][208] ============
__global__ __launch_bounds__(256) void k_att1v4(const u16* __restrict__ encbf,
    const u16* __restrict__ Wea, const float* __restrict__ bea, u16* __restrict__ att1T){
  int mb = blockIdx.x >> 2, nb = blockIdx.x & 3;
  int m0 = mb*64;
  __shared__ u16 A[64*136];
  int tid = threadIdx.x, wv = tid>>6, lane = tid&63, lr = lane&15, lh = lane>>4;
  f32x4 acc[4][2];
  #pragma unroll
  for (int mt = 0; mt < 4; mt++){ acc[mt][0] = (f32x4){0,0,0,0}; acc[mt][1] = (f32x4){0,0,0,0}; }
  for (int kc = 0; kc < 16; kc++){
    __syncthreads();
    {
      int row = tid>>2, seg = tid&3;
      const u16* src = encbf + (size_t)(m0 + row)*2048 + kc*128 + seg*32;
      #pragma unroll
      for (int i = 0; i < 4; i++)
        *(bf16x8*)&A[row*136 + seg*32 + i*8] = *(const bf16x8*)(src + i*8);
    }
    __syncthreads();
    #pragma unroll
    for (int ki = 0; ki < 4; ki++){
      bf16x8 av[4];
      #pragma unroll
      for (int mt = 0; mt < 4; mt++)
        av[mt] = *(const bf16x8*)&A[(mt*16 + lr)*136 + ki*32 + lh*8];
      #pragma unroll
      for (int nt = 0; nt < 2; nt++){
        const u16* wp = Wea + (size_t)(nb*128 + wv*32 + nt*16 + lr)*2048 + kc*128 + ki*32 + lh*8;
        bf16x8 bv = *(const bf16x8*)wp;
        #pragma unroll
        for (int mt = 0; mt < 4; mt++) acc[mt][nt] = MF(av[mt], bv, acc[mt][nt]);
      }
    }
  }
  #pragma unroll
  for (int nt = 0; nt < 2; nt++){
    int n = nb*128 + wv*32 + nt*16 + lr;
    float bias = bea[n];
    #pragma unroll
    for (int mt = 0; mt < 4; mt++){
      #pragma unroll
      for (int r = 0; r < 4; r++){
        int m = m0 + mt*16 + lh*4 + r;
        int bb = m / 196, pp = m - bb*196;
        att1T[((size_t)bb*512 + n)*208 + pp] = f2bf(acc[mt][nt][r] + bias);
      }
    }
  }
}

// ============ h,c init v2 (MFMA, on-the-fly fp32->bf16) ============
// grid 16 x 256 thr; jg = blk*64+wv*16 spans 0..1023 (0..511 -> h, 512..1023 -> c)
__global__ __launch_bounds__(256) void k_initv2(const float* __restrict__ encm,
    const float* __restrict__ emb0,
    const float* __restrict__ Wh, const float* __restrict__ bh,
    const float* __restrict__ Wc, const float* __restrict__ bc,
    u16* __restrict__ h_bf, float* __restrict__ c){
  int tid = threadIdx.x, wv = tid>>6, lane = tid&63, lr = lane&15, lh = lane>>4;
  int j = blockIdx.x*64 + wv*16 + lr;     // 0..1023
  const float* wbase = (j < 512) ? (Wh + (size_t)j*XDIM) : (Wc + (size_t)(j-512)*XDIM);
  f32x4 acc0 = {0,0,0,0}, acc1 = {0,0,0,0};
  #pragma unroll 2
  for (int k0 = 0; k0 < XDIM; k0 += 32){
    int k = k0 + lh*8;
    float4 w0 = *(const float4*)(wbase + k);
    float4 w1 = *(const float4*)(wbase + k + 4);
    bf16x8 bv;
    bv[0]=(short)f2bf(w0.x); bv[1]=(short)f2bf(w0.y); bv[2]=(short)f2bf(w0.z); bv[3]=(short)f2bf(w0.w);
    bv[4]=(short)f2bf(w1.x); bv[5]=(short)f2bf(w1.y); bv[6]=(short)f2bf(w1.z); bv[7]=(short)f2bf(w1.w);
    float4 x0, x1, y0, y1;
    if (k < 2048){
      x0 = *(const float4*)(encm + (size_t)lr*2048 + k);
      x1 = *(const float4*)(encm + (size_t)lr*2048 + k + 4);
      y0 = *(const float4*)(encm + (size_t)(16+lr)*2048 + k);
      y1 = *(const float4*)(encm + (size_t)(16+lr)*2048 + k + 4);
    } else {
      int ke = k - 2048;
      x0 = *(const float4*)(emb0 + (size_t)lr*256 + ke);
      x1 = *(const float4*)(emb0 + (size_t)lr*256 + ke + 4);
      y0 = *(const float4*)(emb0 + (size_t)(16+lr)*256 + ke);
      y1 = *(const float4*)(emb0 + (size_t)(16+lr)*256 + ke + 4);
    }
    bf16x8 a0, a1;
    a0[0]=(short)f2bf(x0.x); a0[1]=(short)f2bf(x0.y); a0[2]=(short)f2bf(x0.z); a0[3]=(short)f2bf(x0.w);
    a0[4]=(short)f2bf(x1.x); a0[5]=(short)f2bf(x1.y); a0[6]=(short)f2bf(x1.z); a0[7]=(short)f2bf(x1.w);
    a1[0]=(short)f2bf(y0.x); a1[1]=(short)f2bf(y0.y); a1[2]=(short)f2bf(y0.z); a1[3]=(short)f2bf(y0.w);
    a1[4]=(short)f2bf(y1.x); a1[5]=(short)f2bf(y1.y); a1[6]=(short)f2bf(y1.z); a1[7]=(short)f2bf(y1.w);
    acc0 = MF(a0, bv, acc0);
    acc1 = MF(a1, bv, acc1);
  }
  #pragma unroll
  for (int r = 0; r < 4; ++r){
    int b0 = lh*4 + r, b1 = 16 + b0;
    if (j < 512){
      float bias = bh[j];
      h_bf[(size_t)b0*512 + j] = f2bf(acc0[r] + bias);
      h_bf[(size_t)b1*512 + j] = f2bf(acc1[r] + bias);
    } else {
      int jc = j - 512;
      float bias = bc[jc];
      c[(size_t)b0*512 + jc] = acc0[r] + bias;
      c[(size_t)b1*512 + jc] = acc1[r] + bias;
    }
  }
}

// ============ kAB: fused [kA: pA rows 512..4607 + preds] and [kB1: att2 local + score partials] ============
// grid 321 = 65 kA-role (j0 = 512 + blk*64) + 256 kB1-role (b, ac)
__global__ __launch_bounds__(256) void kAB(const u16* __restrict__ h, const u16* __restrict__ WAP,
    float* __restrict__ pA, const u16* __restrict__ att1T,
    const float* __restrict__ bdec, const float* __restrict__ wfull,
    float* __restrict__ scp, const float* __restrict__ bfc, const float* __restrict__ bstop,
    const int* __restrict__ len, float* __restrict__ out, int t){
  int blk = blockIdx.x, tid = threadIdx.x;
  if (t == 64 && blk != 64) return;      // final call: preds block only
  if (blk < 65){
    // ---- kA role: pA rows 512..4607 (gateRaw|hh) + preds/stop(t-1) ----
    __shared__ u16 HL[32*520];
    int wv = tid>>6, lane = tid&63, lr = lane&15, lh = lane>>4;
    for (int i = tid; i < 4096; i += 256){
      unsigned long long v = ((const unsigned long long*)h)[i];
      int row = i >> 7, col = (i & 127)*4;
      *(unsigned long long*)&HL[row*520 + col] = v;
    }
    __syncthreads();
    int j0 = 512 + blk*64 + wv*16;
    f32x4 acc0 = {0,0,0,0}, acc1 = {0,0,0,0};
    #pragma unroll 4
    for (int ki = 0; ki < 16; ++ki){
      bf16x8 bv = *(const bf16x8*)&WAP[(size_t)(j0+lr)*512 + ki*32 + lh*8];
      bf16x8 a0 = *(const bf16x8*)&HL[lr*520 + ki*32 + lh*8];
      bf16x8 a1 = *(const bf16x8*)&HL[(16+lr)*520 + ki*32 + lh*8];
      acc0 = MF(a0, bv, acc0);
      acc1 = MF(a1, bv, acc1);
    }
    int j = j0 + lr;
    if (j < 4608){
      #pragma unroll
      for (int r = 0; r < 4; ++r){
        pA[(size_t)(lh*4+r)*4608 + j]    = acc0[r];
        pA[(size_t)(lh*4+r+16)*4608 + j] = acc1[r];
      }
    } else if (j < 4611 && t > 0){
      int jj = j - 4608, tm1 = t - 1;
      #pragma unroll
      for (int r = 0; r < 4; ++r){
        #pragma unroll
        for (int hb = 0; hb < 2; ++hb){
          int b0 = lh*4 + r + hb*16;
          float val = hb ? acc1[r] : acc0[r];
          bool mk = tm1 < len[b0];
          if (jj < 2) out[O_PRED + ((size_t)b0*64 + tm1)*2 + jj] = mk ? val + bfc[jj] : 0.f;
          else        out[O_STOP + (size_t)b0*64 + tm1] =
                        mk ? 1.f/(1.f + expf(-(val + bstop[0]))) : 0.f;
        }
      }
    }
  } else {
    // ---- kB1 role: local att2 + score partials, coalesced along p ----
    int kb = blk - 65, b = kb >> 3, ac = kb & 7;
    if (t >= len[b]) return;
    __shared__ u16 hL[512];
    __shared__ float a2s[64], wfs[64];
    if (tid < 128)
      ((unsigned long long*)hL)[tid] = ((const unsigned long long*)(h + (size_t)b*512))[tid];
    if (tid < 64) wfs[tid] = wfull[ac*64 + tid];
    __syncthreads();
    {
      int a = tid >> 2, q = tid & 3;
      const u16* wrow = WAP + (size_t)(ac*64 + a)*512 + q*128;
      const u16* hrow = hL + q*128;
      float acc = 0.f;
      #pragma unroll
      for (int i = 0; i < 16; ++i){
        bf16x8 wv8 = *(const bf16x8*)(wrow + i*8);
        bf16x8 hv8 = *(const bf16x8*)(hrow + i*8);
        #pragma unroll
        for (int e = 0; e < 8; ++e) acc += bf2f((u16)hv8[e]) * bf2f((u16)wv8[e]);
      }
      acc += __shfl_xor(acc, 1);
      acc += __shfl_xor(acc, 2);
      if (q == 0) a2s[a] = acc + bdec[ac*64 + a];
    }
    __syncthreads();
    int p = tid;
    if (p < 196){
      const u16* col = att1T + ((size_t)b*512 + ac*64)*208 + p;
      float acc = 0.f;
      #pragma unroll 8
      for (int a = 0; a < 64; ++a)
        acc += fmaxf(bf2f(col[(size_t)a*208]) + a2s[a], 0.f) * wfs[a];
      scp[(size_t)(b*8 + ac)*200 + p] = acc;
    }
  }
}

// ============ kB2: softmax + awe + gate -> xa ; alphas ============
__global__ __launch_bounds__(256) void kB2(const float* __restrict__ scp,
    const float* __restrict__ pA, const u16* __restrict__ encbf,
    const float* __restrict__ bfull, const float* __restrict__ bfb,
    u16* __restrict__ xa, const int* __restrict__ len, float* __restrict__ out, int t){
  int b = blockIdx.x >> 3, dc = blockIdx.x & 7;
  int tid = threadIdx.x, wv = tid>>6, lane = tid&63;
  if (t >= len[b]){
    if (dc == 0 && tid < 196) out[O_ALPHA + ((size_t)b*64 + t)*196 + tid] = 0.f;
    return;
  }
  __shared__ float ev[200], redf[4], bcx[2];
  float s = -1e30f;
  if (tid < 196){
    s = bfull[0];
    #pragma unroll
    for (int q = 0; q < 8; ++q) s += scp[(size_t)(b*8 + q)*200 + tid];
  }
  float m = s;
  #pragma unroll
  for (int o = 32; o; o >>= 1) m = fmaxf(m, __shfl_down(m, o));
  if (lane == 0) redf[wv] = m;
  __syncthreads();
  if (tid == 0) bcx[0] = fmaxf(fmaxf(redf[0],redf[1]), fmaxf(redf[2],redf[3]));
  __syncthreads();
  float e = (tid < 196) ? expf(s - bcx[0]) : 0.f;
  if (tid < 200) ev[tid] = (tid < 196) ? e : 0.f;
  float sm = e;
  #pragma unroll
  for (int o = 32; o; o >>= 1) sm += __shfl_down(sm, o);
  __syncthreads();
  if (lane == 0) redf[wv] = sm;
  __syncthreads();
  if (tid == 0) bcx[1] = redf[0]+redf[1]+redf[2]+redf[3];
  __syncthreads();
  float ssum = bcx[1];
  int d = dc*256 + tid;
  const u16* ep = encbf + (size_t)(b*196)*ENCD + d;
  float q[8];
  #pragma unroll
  for (int j = 0; j < 8; ++j) q[j] = 0.f;
  #pragma unroll 2
  for (int p = 0; p < 192; p += 8){
    #pragma unroll
    for (int j = 0; j < 8; ++j)
      q[j] += ev[p+j]*bf2f(ep[(size_t)(p+j)*ENCD]);
  }
  #pragma unroll
  for (int j = 0; j < 4; ++j)
    q[j] += ev[192+j]*bf2f(ep[(size_t)(192+j)*ENCD]);
  float awe = (((q[0]+q[1])+(q[2]+q[3])) + ((q[4]+q[5])+(q[6]+q[7]))) / ssum;
  float gp = pA[(size_t)b*4608 + 512 + d] + bfb[d];
  float gate = 1.f/(1.f + expf(-gp));
  xa[(size_t)b*2048 + d] = f2bf(gate * awe);
  if (dc == 0 && tid < 196) out[O_ALPHA + ((size_t)b*64 + t)*196 + tid] = ev[tid]/ssum;
}

// ============ kC: gates GEMM (8-wave K-split) + LSTM fused ============
__global__ __launch_bounds__(512) void kC(const u16* __restrict__ xa,
    const u16* __restrict__ hc, u16* __restrict__ hn, float* __restrict__ c,
    const u16* __restrict__ WIH2, const float* __restrict__ pA,
    const float* __restrict__ bcomb, const u16* __restrict__ gemb,
    const int* __restrict__ len, int t){
  int tid = threadIdx.x, wv = tid>>6, lane = tid&63, lr = lane&15, lh = lane>>4;
  int jp0 = blockIdx.x*16;
  __shared__ float red[8*512];
  f32x4 acc0 = {0,0,0,0}, acc1 = {0,0,0,0};
  #pragma unroll
  for (int ks = 0; ks < 8; ++ks){
    int k = wv*256 + ks*32;
    bf16x8 a0 = *(const bf16x8*)&xa[(size_t)lr*2048 + k + lh*8];
    bf16x8 a1 = *(const bf16x8*)&xa[(size_t)(16+lr)*2048 + k + lh*8];
    bf16x8 bv = *(const bf16x8*)&WIH2[(size_t)(jp0+lr)*2048 + k + lh*8];
    acc0 = MF(a0, bv, acc0);
    acc1 = MF(a1, bv, acc1);
  }
  #pragma unroll
  for (int r = 0; r < 4; ++r){
    red[wv*512 + ((lh*4+r) << 4) + lr]    = acc0[r];
    red[wv*512 + ((16+lh*4+r) << 4) + lr] = acc1[r];
  }
  __syncthreads();
  {
    int b = tid >> 4, jl = tid & 15, e = jl & 3;
    int jp = jp0 + jl, u = jp >> 2;
    float g = 0.f;
    #pragma unroll
    for (int w = 0; w < 8; ++w) g += red[w*512 + tid];
    g += bcomb[jp] + bf2f(gemb[((size_t)b*64 + t)*2048 + jp])
       + pA[(size_t)b*4608 + 2560 + e*512 + u];
    float sv = (e == 2) ? tanhf(g) : 1.f/(1.f + expf(-g));
    float vb = __shfl_xor(sv, 1), vc = __shfl_xor(sv, 2), vd = __shfl_xor(vb, 2);
    float i_s = (e==0)?sv:(e==1)?vb:(e==2)?vc:vd;
    float f_s = (e==1)?sv:(e==0)?vb:(e==3)?vc:vd;
    float g_t = (e==2)?sv:(e==3)?vb:(e==0)?vc:vd;
    float o_s = (e==3)?sv:(e==2)?vb:(e==1)?vc:vd;
    float cold = c[(size_t)b*512 + u];
    float hold = bf2f(hc[(size_t)b*512 + u]);
    bool mk = t < len[b];
    float cn = mk ? (f_s*cold + i_s*g_t) : cold;
    float hv = mk ? (o_s * tanhf(cn)) : hold;
    if (e == 0){
      c[(size_t)b*512 + u] = cn;
      hn[(size_t)b*512 + u] = f2bf(hv);
    }
  }
}

// ================= host launcher =================
extern "C" void kernel_launch(void* const* d_in, const int* in_sizes, int n_in,
                              void* d_out, int out_size, void* d_ws, size_t ws_size,
                              hipStream_t stream){
  (void)in_sizes; (void)n_in; (void)out_size; (void)ws_size;
  const float* enc_out   = (const float*)d_in[0];
  const float* imgs      = (const float*)d_in[1];
  const int*   seq       = (const int*)d_in[2];
  const float* seqoff    = (const float*)d_in[3];
  const int*   caplen    = (const int*)d_in[4];
  const float* W_pe      = (const float*)d_in[5];
  const float* b_pe      = (const float*)d_in[6];
  const float* W_enc_att = (const float*)d_in[7];
  const float* b_enc_att = (const float*)d_in[8];
  const float* W_dec_att = (const float*)d_in[9];
  const float* b_dec_att = (const float*)d_in[10];
  const float* w_full    = (const float*)d_in[11];
  const float* b_full    = (const float*)d_in[12];
  const float* W_init_h  = (const float*)d_in[13];
  const float* b_init_h  = (const float*)d_in[14];
  const float* W_init_c  = (const float*)d_in[15];
  const float* b_init_c  = (const float*)d_in[16];
  const float* W_fb      = (const float*)d_in[17];
  const float* b_fb      = (const float*)d_in[18];
  const float* W_ih      = (const float*)d_in[19];
  const float* b_ih      = (const float*)d_in[20];
  const float* W_hh      = (const float*)d_in[21];
  const float* b_hh      = (const float*)d_in[22];
  const float* W_fc      = (const float*)d_in[23];
  const float* b_fc      = (const float*)d_in[24];
  const float* W_stop    = (const float*)d_in[25];
  const float* b_stop    = (const float*)d_in[26];

  float* out = (float*)d_out;
  float* ws  = (float*)d_ws;
  int*   wsi = (int*)d_ws;
  u16*   us  = (u16*)d_ws;

  u16* H[2] = { us + US_H0, us + US_H1 };

  k_prep<<<1, 64, 0, stream>>>(caplen, wsi + WS_SORT, wsi + WS_LEN, out);
  k_seqoff<<<16, 256, 0, stream>>>(seqoff, wsi + WS_SORT, out);
  k_encbf<<<6272, 256, 0, stream>>>(enc_out, wsi + WS_SORT, us + US_ENC);
  k_encmean<<<256, 256, 0, stream>>>(us + US_ENC, ws + WS_ENCM);
  k_patch<<<2048, 256, 0, stream>>>(imgs, seq, wsi + WS_SORT, us + US_PATCH);
  k_embedv2<<<128, 256, 0, stream>>>(us + US_PATCH, W_pe, b_pe, us + US_EMBBF, ws + WS_EMB0);
  k_cvt2<<<7240, 256, 0, stream>>>(W_ih, W_hh, W_dec_att, W_fb, W_fc, W_stop, W_enc_att,
                                   b_ih, b_hh,
                                   us + US_WIH2, us + US_WIHE, us + US_WAP,
                                   us + US_WEA, ws + WS_BCOMB);
  k_att1v4<<<392, 256, 0, stream>>>(us + US_ENC, us + US_WEA, b_enc_att, us + US_ATT1T);
  k_gemb<<<256, 256, 0, stream>>>(us + US_EMBBF, us + US_WIHE, us + US_GEMB);
  k_initv2<<<16, 256, 0, stream>>>(ws + WS_ENCM, ws + WS_EMB0, W_init_h, b_init_h,
                                   W_init_c, b_init_c, H[0], ws + WS_C);

  for (int t = 0; t < Tn; ++t){
    kAB<<<321, 256, 0, stream>>>(H[t & 1], us + US_WAP, ws + WS_PA, us + US_ATT1T,
                                 b_dec_att, w_full, ws + WS_SCP, b_fc, b_stop,
                                 wsi + WS_LEN, out, t);
    kB2<<<256, 256, 0, stream>>>(ws + WS_SCP, ws + WS_PA, us + US_ENC, b_full, b_fb,
                                 us + US_XA, wsi + WS_LEN, out, t);
    kC<<<128, 512, 0, stream>>>(us + US_XA, H[t & 1], H[(t + 1) & 1], ws + WS_C,
                                us + US_WIH2, ws + WS_PA, ws + WS_BCOMB, us + US_GEMB,
                                wsi + WS_LEN, t);
  }
  kAB<<<321, 256, 0, stream>>>(H[0], us + US_WAP, ws + WS_PA, us + US_ATT1T,
                               b_dec_att, w_full, ws + WS_SCP, b_fc, b_stop,
                               wsi + WS_LEN, out, 64);
}

// Round 13
// 1979.951 us; speedup vs baseline: 1.2965x; 1.0150x over previous
//
#include <hip/hip_runtime.h>

// ---------------- problem constants ----------------
#define Bn 32
#define Tn 64
#define Pn 196
#define ENCD 2048
#define DECD 512
#define XDIM 2304

typedef unsigned short u16;
typedef __attribute__((ext_vector_type(8))) short bf16x8;
typedef __attribute__((ext_vector_type(4))) float f32x4;

#define MF(a,b,c) __builtin_amdgcn_mfma_f32_16x16x32_bf16(a,b,c,0,0,0)

static __device__ __forceinline__ u16 f2bf(float f){
  unsigned int u = __float_as_uint(f);
  unsigned int r = u + 0x7FFFu + ((u >> 16) & 1u);
  return (u16)(r >> 16);
}
static __device__ __forceinline__ float bf2f(u16 u){
  return __uint_as_float(((unsigned int)u) << 16);
}

// ---------------- output offsets (floats) ----------------
#define O_PRED   0
#define O_STOP   4096
#define O_SEQOFF 6144
#define O_LEN    10240
#define O_ALPHA  10272
#define O_SORT   411680

// ---------------- ws: f32/int region (f32 indices) ----------------
#define WS_SORT    0        // int[32]
#define WS_LEN     32       // int[32]
#define WS_C       64       // f32 [32][512]
#define WS_PA      16448    // f32 [32][4608] (unused 0..511 | gateRaw 512..2559 | hh 2560..4607)
#define WS_SCP     163904   // f32 [32][8][200] score partials
#define WS_ENCM    215104   // f32 [32][2048]
#define WS_EMB0    280640   // f32 [32][256]
#define WS_BCOMB   288832   // f32 [2048]
// ---------------- ws: u16 region (absolute u16 indices from (u16*)d_ws) ----------------
#define US_H0      800000                 // [32][512]
#define US_H1      816384                 // [32][512]
#define US_XA      832768                 // [32][2048]
#define US_EMBBF   898304                 // [32][64][256]
#define US_ATT1T   1422592                // [32][512][208] transposed att1
#define US_ENC     4830464                // [6272][2048] sorted row-major
#define US_WAP     17675520               // [4672][512] Wdec|Wfb|Whh|Wfc(2)|Wstop|pad
#define US_WIHE    20067584               // [2048][256]  jp-interleaved
#define US_WIH2    20591872               // [2048][2048] jp-interleaved
#define US_GEMB    24786176               // [32*64][2048]
#define US_PATCH   20591872               // [2048][3072] ALIAS over WIH2+GEMB head (pre-cvt2)
#define US_WPEB    26883328               // [256][3072] bf16 W_pe — in gap after PATCH, before WEA (pre-gemb)
#define US_WEA     27931904               // [512][2048]  ALIAS in GEMB tail (pre-gemb)

// ============ prep: stable descending sort ============
__global__ void k_prep(const int* __restrict__ caplen, int* __restrict__ ws_sort,
                       int* __restrict__ ws_len, float* __restrict__ out){
  __shared__ int len[32];
  int i = threadIdx.x;
  if (i < 32) len[i] = caplen[i];
  __syncthreads();
  if (i < 32){
    int li = len[i], r = 0;
    for (int j = 0; j < 32; j++){
      int lj = len[j];
      r += (lj > li) || (lj == li && j < i);
    }
    ws_sort[r] = i;
    ws_len[r]  = li;
    out[O_LEN + r]  = (float)li;
    out[O_SORT + r] = (float)i;
  }
}

__global__ void k_seqoff(const float* __restrict__ seqoff, const int* __restrict__ ws_sort,
                         float* __restrict__ out){
  int idx = blockIdx.x*256 + threadIdx.x;
  int b = idx >> 7, r = idx & 127;
  out[O_SEQOFF + idx] = seqoff[ws_sort[b]*128 + r];
}

// ============ enc -> sorted row-major bf16 [6272][2048] ============
__global__ void k_encbf(const float* __restrict__ enc, const int* __restrict__ srt,
                        u16* __restrict__ dst){
  int m = blockIdx.x;
  int b = m / 196, p = m - b*196;
  const float* src = enc + ((size_t)srt[b]*196 + p)*ENCD;
  u16* d = dst + (size_t)m*ENCD;
  int i = threadIdx.x*8;
  float4 v0 = *(const float4*)(src + i);
  float4 v1 = *(const float4*)(src + i + 4);
  bf16x8 s;
  s[0]=(short)f2bf(v0.x); s[1]=(short)f2bf(v0.y); s[2]=(short)f2bf(v0.z); s[3]=(short)f2bf(v0.w);
  s[4]=(short)f2bf(v1.x); s[5]=(short)f2bf(v1.y); s[6]=(short)f2bf(v1.z); s[7]=(short)f2bf(v1.w);
  *(bf16x8*)(d + i) = s;
}

__global__ void k_encmean(const u16* __restrict__ encbf, float* __restrict__ encm){
  int b = blockIdx.x >> 3, dc = blockIdx.x & 7;
  int d = dc*256 + threadIdx.x;
  const u16* ep = encbf + (size_t)(b*196)*ENCD + d;
  float s = 0.f;
  #pragma unroll 4
  for (int p = 0; p < Pn; p++) s += bf2f(ep[(size_t)p*ENCD]);
  encm[b*ENCD + d] = s * (1.f/196.f);
}

// ============ patch extraction -> bf16 ============
__global__ void k_patch(const float* __restrict__ imgs, const int* __restrict__ seq,
                        const int* __restrict__ srt, u16* __restrict__ patches){
  int blk = blockIdx.x; int b = blk>>6, t = blk&63;
  int sb = srt[b];
  int x0 = seq[(sb*64+t)*2 + 0], y0 = seq[(sb*64+t)*2 + 1];
  const float* img = imgs + (size_t)sb*3*512*512;
  u16* dst = patches + (size_t)(b*64+t)*3072;
  for (int idx = threadIdx.x; idx < 3072; idx += 256){
    int c = idx>>10, rem = idx&1023, i = rem>>5, j = rem&31;
    int yy = y0 + i - 24, xx = x0 + j - 24;
    float v = 0.f;
    if ((unsigned)yy < 512u && (unsigned)xx < 512u) v = img[((size_t)c*512 + yy)*512 + xx];
    dst[idx] = f2bf(v);
  }
}

// ============ W_pe -> bf16 [256][3072] ============
__global__ __launch_bounds__(256) void k_wpeb(const float* __restrict__ W_pe,
                                              u16* __restrict__ wpeb){
  int i = (blockIdx.x*256 + threadIdx.x)*4;
  float4 v = *(const float4*)(W_pe + i);
  wpeb[i+0] = f2bf(v.x); wpeb[i+1] = f2bf(v.y);
  wpeb[i+2] = f2bf(v.z); wpeb[i+3] = f2bf(v.w);
}

// ============ embed GEMM v3 (all-bf16 MFMA, att1v4-style) ============
// grid 128 = 32 mb(64 rows = one batch) x 4 nb(64 n); wave owns 16 n
__global__ __launch_bounds__(256) void k_embedv3(const u16* __restrict__ patches,
    const u16* __restrict__ wpeb, const float* __restrict__ b_pe,
    u16* __restrict__ embbf, float* __restrict__ emb0){
  int mb = blockIdx.x >> 2, nb = blockIdx.x & 3;
  int m0 = mb*64;
  __shared__ u16 A[64*136];
  int tid = threadIdx.x, wv = tid>>6, lane = tid&63, lr = lane&15, lh = lane>>4;
  f32x4 acc[4];
  #pragma unroll
  for (int mt = 0; mt < 4; mt++) acc[mt] = (f32x4){0,0,0,0};
  for (int kc = 0; kc < 24; kc++){
    __syncthreads();
    {
      int row = tid>>2, seg = tid&3;
      const u16* src = patches + (size_t)(m0 + row)*3072 + kc*128 + seg*32;
      #pragma unroll
      for (int i = 0; i < 4; i++)
        *(bf16x8*)&A[row*136 + seg*32 + i*8] = *(const bf16x8*)(src + i*8);
    }
    __syncthreads();
    #pragma unroll
    for (int ki = 0; ki < 4; ki++){
      bf16x8 bv = *(const bf16x8*)&wpeb[(size_t)(nb*64 + wv*16 + lr)*3072 + kc*128 + ki*32 + lh*8];
      #pragma unroll
      for (int mt = 0; mt < 4; mt++){
        bf16x8 av = *(const bf16x8*)&A[(mt*16 + lr)*136 + ki*32 + lh*8];
        acc[mt] = MF(av, bv, acc[mt]);
      }
    }
  }
  int n = nb*64 + wv*16 + lr;
  float bias = b_pe[n];
  #pragma unroll
  for (int mt = 0; mt < 4; mt++){
    #pragma unroll
    for (int r = 0; r < 4; r++){
      int t = mt*16 + lh*4 + r;
      float val = acc[mt][r] + bias;
      embbf[(size_t)(m0 + t)*256 + n] = f2bf(val);
      if (t == 0) emb0[mb*256 + n] = val;
    }
  }
}

// ============ weight converts ============
__global__ void k_cvt2(const float* __restrict__ Wih, const float* __restrict__ Whh,
    const float* __restrict__ Wdec, const float* __restrict__ Wfb,
    const float* __restrict__ Wfc, const float* __restrict__ Wstop,
    const float* __restrict__ Wea, const float* __restrict__ bih, const float* __restrict__ bhh,
    u16* __restrict__ WIH2, u16* __restrict__ WIHE,
    u16* __restrict__ WAP, u16* __restrict__ WEAd, float* __restrict__ bcomb){
  int blk = blockIdx.x, tid = threadIdx.x;
  if (blk < 2048){
    int r = blk, jp = (r & 511)*4 + (r >> 9);
    for (int i = tid; i < 2304; i += 256){
      u16 v = f2bf(Wih[(size_t)r*2304 + i]);
      if (i < 2048) WIH2[(size_t)jp*2048 + i] = v;
      else          WIHE[(size_t)jp*256 + (i - 2048)] = v;
    }
  } else if (blk < 6720){
    int j = blk - 2048;
    const float* src;
    if (j < 512)        src = Wdec + (size_t)j*512;
    else if (j < 2560)  src = Wfb + (size_t)(j-512)*512;
    else if (j < 4608)  src = Whh + (size_t)(j-2560)*512;
    else if (j == 4608) src = Wfc;
    else if (j == 4609) src = Wfc + 512;
    else if (j == 4610) src = Wstop;
    else src = 0;
    for (int i = tid; i < 512; i += 256)
      WAP[(size_t)j*512 + i] = src ? f2bf(src[i]) : (u16)0;
  } else if (blk < 7232){
    int r = blk - 6720;
    for (int i = tid; i < 2048; i += 256)
      WEAd[(size_t)r*2048 + i] = f2bf(Wea[(size_t)r*2048 + i]);
  } else {
    int jp = (blk - 7232)*256 + tid;
    int r = (jp & 3)*512 + (jp >> 2);
    bcomb[jp] = bih[r] + bhh[r];
  }
}

// ============ G_emb = emb @ WIHE^T ============
__global__ __launch_bounds__(256) void k_gemb(const u16* __restrict__ embbf,
    const u16* __restrict__ WIHE, u16* __restrict__ gemb){
  int m0 = (blockIdx.x >> 3)*64, n0 = (blockIdx.x & 7)*256;
  __shared__ u16 A[64*264];
  int tid = threadIdx.x, wv = tid>>6, lane = tid&63, lr = lane&15, lh = lane>>4;
  {
    int row = tid>>2, seg = tid&3;
    const u16* src = embbf + (size_t)(m0 + row)*256 + seg*64;
    #pragma unroll
    for (int i = 0; i < 8; i++)
      *(bf16x8*)&A[row*264 + seg*64 + i*8] = *(const bf16x8*)(src + i*8);
  }
  __syncthreads();
  f32x4 acc[4][4];
  #pragma unroll
  for (int mt = 0; mt < 4; mt++)
    #pragma unroll
    for (int nt = 0; nt < 4; nt++) acc[mt][nt] = (f32x4){0,0,0,0};
  #pragma unroll
  for (int ki = 0; ki < 8; ki++){
    bf16x8 av[4];
    #pragma unroll
    for (int mt = 0; mt < 4; mt++)
      av[mt] = *(const bf16x8*)&A[(mt*16 + lr)*264 + ki*32 + lh*8];
    #pragma unroll
    for (int nt = 0; nt < 4; nt++){
      bf16x8 bv = *(const bf16x8*)&WIHE[(size_t)(n0 + wv*64 + nt*16 + lr)*256 + ki*32 + lh*8];
      #pragma unroll
      for (int mt = 0; mt < 4; mt++) acc[mt][nt] = MF(av[mt], bv, acc[mt][nt]);
    }
  }
  #pragma unroll
  for (int nt = 0; nt < 4; nt++){
    int n = n0 + wv*64 + nt*16 + lr;
    #pragma unroll
    for (int mt = 0; mt < 4; mt++)
      #pragma unroll
      for (int r = 0; r < 4; r++)
        gemb[(size_t)(m0 + mt*16 + lh*4 + r)*2048 + n] = f2bf(acc[mt][nt][r]);
  }
}

// ============ att1 v4 (bf16 source, N-split 4) -> TRANSPOSED att1T[b][512][208] ============
__global__ __launch_bounds__(256) void k_att1v4(const u16* __restrict__ encbf,
    const u16* __restrict__ Wea, const float* __restrict__ bea, u16* __restrict__ att1T){
  int mb = blockIdx.x >> 2, nb = blockIdx.x & 3;
  int m0 = mb*64;
  __shared__ u16 A[64*136];
  int tid = threadIdx.x, wv = tid>>6, lane = tid&63, lr = lane&15, lh = lane>>4;
  f32x4 acc[4][2];
  #pragma unroll
  for (int mt = 0; mt < 4; mt++){ acc[mt][0] = (f32x4){0,0,0,0}; acc[mt][1] = (f32x4){0,0,0,0}; }
  for (int kc = 0; kc < 16; kc++){
    __syncthreads();
    {
      int row = tid>>2, seg = tid&3;
      const u16* src = encbf + (size_t)(m0 + row)*2048 + kc*128 + seg*32;
      #pragma unroll
      for (int i = 0; i < 4; i++)
        *(bf16x8*)&A[row*136 + seg*32 + i*8] = *(const bf16x8*)(src + i*8);
    }
    __syncthreads();
    #pragma unroll
    for (int ki = 0; ki < 4; ki++){
      bf16x8 av[4];
      #pragma unroll
      for (int mt = 0; mt < 4; mt++)
        av[mt] = *(const bf16x8*)&A[(mt*16 + lr)*136 + ki*32 + lh*8];
      #pragma unroll
      for (int nt = 0; nt < 2; nt++){
        const u16* wp = Wea + (size_t)(nb*128 + wv*32 + nt*16 + lr)*2048 + kc*128 + ki*32 + lh*8;
        bf16x8 bv = *(const bf16x8*)wp;
        #pragma unroll
        for (int mt = 0; mt < 4; mt++) acc[mt][nt] = MF(av[mt], bv, acc[mt][nt]);
      }
    }
  }
  #pragma unroll
  for (int nt = 0; nt < 2; nt++){
    int n = nb*128 + wv*32 + nt*16 + lr;
    float bias = bea[n];
    #pragma unroll
    for (int mt = 0; mt < 4; mt++){
      #pragma unroll
      for (int r = 0; r < 4; r++){
        int m = m0 + mt*16 + lh*4 + r;
        int bb = m / 196, pp = m - bb*196;
        att1T[((size_t)bb*512 + n)*208 + pp] = f2bf(acc[mt][nt][r] + bias);
      }
    }
  }
}

// ============ h,c init v2 (MFMA, on-the-fly fp32->bf16) ============
__global__ __launch_bounds__(256) void k_initv2(const float* __restrict__ encm,
    const float* __restrict__ emb0,
    const float* __restrict__ Wh, const float* __restrict__ bh,
    const float* __restrict__ Wc, const float* __restrict__ bc,
    u16* __restrict__ h_bf, float* __restrict__ c){
  int tid = threadIdx.x, wv = tid>>6, lane = tid&63, lr = lane&15, lh = lane>>4;
  int j = blockIdx.x*64 + wv*16 + lr;     // 0..1023
  const float* wbase = (j < 512) ? (Wh + (size_t)j*XDIM) : (Wc + (size_t)(j-512)*XDIM);
  f32x4 acc0 = {0,0,0,0}, acc1 = {0,0,0,0};
  #pragma unroll 2
  for (int k0 = 0; k0 < XDIM; k0 += 32){
    int k = k0 + lh*8;
    float4 w0 = *(const float4*)(wbase + k);
    float4 w1 = *(const float4*)(wbase + k + 4);
    bf16x8 bv;
    bv[0]=(short)f2bf(w0.x); bv[1]=(short)f2bf(w0.y); bv[2]=(short)f2bf(w0.z); bv[3]=(short)f2bf(w0.w);
    bv[4]=(short)f2bf(w1.x); bv[5]=(short)f2bf(w1.y); bv[6]=(short)f2bf(w1.z); bv[7]=(short)f2bf(w1.w);
    float4 x0, x1, y0, y1;
    if (k < 2048){
      x0 = *(const float4*)(encm + (size_t)lr*2048 + k);
      x1 = *(const float4*)(encm + (size_t)lr*2048 + k + 4);
      y0 = *(const float4*)(encm + (size_t)(16+lr)*2048 + k);
      y1 = *(const float4*)(encm + (size_t)(16+lr)*2048 + k + 4);
    } else {
      int ke = k - 2048;
      x0 = *(const float4*)(emb0 + (size_t)lr*256 + ke);
      x1 = *(const float4*)(emb0 + (size_t)lr*256 + ke + 4);
      y0 = *(const float4*)(emb0 + (size_t)(16+lr)*256 + ke);
      y1 = *(const float4*)(emb0 + (size_t)(16+lr)*256 + ke + 4);
    }
    bf16x8 a0, a1;
    a0[0]=(short)f2bf(x0.x); a0[1]=(short)f2bf(x0.y); a0[2]=(short)f2bf(x0.z); a0[3]=(short)f2bf(x0.w);
    a0[4]=(short)f2bf(x1.x); a0[5]=(short)f2bf(x1.y); a0[6]=(short)f2bf(x1.z); a0[7]=(short)f2bf(x1.w);
    a1[0]=(short)f2bf(y0.x); a1[1]=(short)f2bf(y0.y); a1[2]=(short)f2bf(y0.z); a1[3]=(short)f2bf(y0.w);
    a1[4]=(short)f2bf(y1.x); a1[5]=(short)f2bf(y1.y); a1[6]=(short)f2bf(y1.z); a1[7]=(short)f2bf(y1.w);
    acc0 = MF(a0, bv, acc0);
    acc1 = MF(a1, bv, acc1);
  }
  #pragma unroll
  for (int r = 0; r < 4; ++r){
    int b0 = lh*4 + r, b1 = 16 + b0;
    if (j < 512){
      float bias = bh[j];
      h_bf[(size_t)b0*512 + j] = f2bf(acc0[r] + bias);
      h_bf[(size_t)b1*512 + j] = f2bf(acc1[r] + bias);
    } else {
      int jc = j - 512;
      float bias = bc[jc];
      c[(size_t)b0*512 + jc] = acc0[r] + bias;
      c[(size_t)b1*512 + jc] = acc1[r] + bias;
    }
  }
}

// ============ kAB: fused [kA: pA rows 512..4607 + preds] and [kB1: att2 local + score partials] ============
__global__ __launch_bounds__(256) void kAB(const u16* __restrict__ h, const u16* __restrict__ WAP,
    float* __restrict__ pA, const u16* __restrict__ att1T,
    const float* __restrict__ bdec, const float* __restrict__ wfull,
    float* __restrict__ scp, const float* __restrict__ bfc, const float* __restrict__ bstop,
    const int* __restrict__ len, float* __restrict__ out, int t){
  int blk = blockIdx.x, tid = threadIdx.x;
  if (t == 64 && blk != 64) return;      // final call: preds block only
  if (blk < 65){
    __shared__ u16 HL[32*520];
    int wv = tid>>6, lane = tid&63, lr = lane&15, lh = lane>>4;
    for (int i = tid; i < 4096; i += 256){
      unsigned long long v = ((const unsigned long long*)h)[i];
      int row = i >> 7, col = (i & 127)*4;
      *(unsigned long long*)&HL[row*520 + col] = v;
    }
    __syncthreads();
    int j0 = 512 + blk*64 + wv*16;
    f32x4 acc0 = {0,0,0,0}, acc1 = {0,0,0,0};
    #pragma unroll 4
    for (int ki = 0; ki < 16; ++ki){
      bf16x8 bv = *(const bf16x8*)&WAP[(size_t)(j0+lr)*512 + ki*32 + lh*8];
      bf16x8 a0 = *(const bf16x8*)&HL[lr*520 + ki*32 + lh*8];
      bf16x8 a1 = *(const bf16x8*)&HL[(16+lr)*520 + ki*32 + lh*8];
      acc0 = MF(a0, bv, acc0);
      acc1 = MF(a1, bv, acc1);
    }
    int j = j0 + lr;
    if (j < 4608){
      #pragma unroll
      for (int r = 0; r < 4; ++r){
        pA[(size_t)(lh*4+r)*4608 + j]    = acc0[r];
        pA[(size_t)(lh*4+r+16)*4608 + j] = acc1[r];
      }
    } else if (j < 4611 && t > 0){
      int jj = j - 4608, tm1 = t - 1;
      #pragma unroll
      for (int r = 0; r < 4; ++r){
        #pragma unroll
        for (int hb = 0; hb < 2; ++hb){
          int b0 = lh*4 + r + hb*16;
          float val = hb ? acc1[r] : acc0[r];
          bool mk = tm1 < len[b0];
          if (jj < 2) out[O_PRED + ((size_t)b0*64 + tm1)*2 + jj] = mk ? val + bfc[jj] : 0.f;
          else        out[O_STOP + (size_t)b0*64 + tm1] =
                        mk ? 1.f/(1.f + expf(-(val + bstop[0]))) : 0.f;
        }
      }
    }
  } else {
    int kb = blk - 65, b = kb >> 3, ac = kb & 7;
    if (t >= len[b]) return;
    __shared__ u16 hL[512];
    __shared__ float a2s[64], wfs[64];
    if (tid < 128)
      ((unsigned long long*)hL)[tid] = ((const unsigned long long*)(h + (size_t)b*512))[tid];
    if (tid < 64) wfs[tid] = wfull[ac*64 + tid];
    __syncthreads();
    {
      int a = tid >> 2, q = tid & 3;
      const u16* wrow = WAP + (size_t)(ac*64 + a)*512 + q*128;
      const u16* hrow = hL + q*128;
      float acc = 0.f;
      #pragma unroll
      for (int i = 0; i < 16; ++i){
        bf16x8 wv8 = *(const bf16x8*)(wrow + i*8);
        bf16x8 hv8 = *(const bf16x8*)(hrow + i*8);
        #pragma unroll
        for (int e = 0; e < 8; ++e) acc += bf2f((u16)hv8[e]) * bf2f((u16)wv8[e]);
      }
      acc += __shfl_xor(acc, 1);
      acc += __shfl_xor(acc, 2);
      if (q == 0) a2s[a] = acc + bdec[ac*64 + a];
    }
    __syncthreads();
    int p = tid;
    if (p < 196){
      const u16* col = att1T + ((size_t)b*512 + ac*64)*208 + p;
      float acc = 0.f;
      #pragma unroll 8
      for (int a = 0; a < 64; ++a)
        acc += fmaxf(bf2f(col[(size_t)a*208]) + a2s[a], 0.f) * wfs[a];
      scp[(size_t)(b*8 + ac)*200 + p] = acc;
    }
  }
}

// ============ kB2: softmax + awe + gate -> xa ; alphas ============
__global__ __launch_bounds__(256) void kB2(const float* __restrict__ scp,
    const float* __restrict__ pA, const u16* __restrict__ encbf,
    const float* __restrict__ bfull, const float* __restrict__ bfb,
    u16* __restrict__ xa, const int* __restrict__ len, float* __restrict__ out, int t){
  int b = blockIdx.x >> 3, dc = blockIdx.x & 7;
  int tid = threadIdx.x, wv = tid>>6, lane = tid&63;
  if (t >= len[b]){
    if (dc == 0 && tid < 196) out[O_ALPHA + ((size_t)b*64 + t)*196 + tid] = 0.f;
    return;
  }
  __shared__ float ev[200], redf[4], bcx[2];
  float s = -1e30f;
  if (tid < 196){
    s = bfull[0];
    #pragma unroll
    for (int q = 0; q < 8; ++q) s += scp[(size_t)(b*8 + q)*200 + tid];
  }
  float m = s;
  #pragma unroll
  for (int o = 32; o; o >>= 1) m = fmaxf(m, __shfl_down(m, o));
  if (lane == 0) redf[wv] = m;
  __syncthreads();
  if (tid == 0) bcx[0] = fmaxf(fmaxf(redf[0],redf[1]), fmaxf(redf[2],redf[3]));
  __syncthreads();
  float e = (tid < 196) ? expf(s - bcx[0]) : 0.f;
  if (tid < 200) ev[tid] = (tid < 196) ? e : 0.f;
  float sm = e;
  #pragma unroll
  for (int o = 32; o; o >>= 1) sm += __shfl_down(sm, o);
  __syncthreads();
  if (lane == 0) redf[wv] = sm;
  __syncthreads();
  if (tid == 0) bcx[1] = redf[0]+redf[1]+redf[2]+redf[3];
  __syncthreads();
  float ssum = bcx[1];
  int d = dc*256 + tid;
  const u16* ep = encbf + (size_t)(b*196)*ENCD + d;
  float q[8];
  #pragma unroll
  for (int j = 0; j < 8; ++j) q[j] = 0.f;
  #pragma unroll 2
  for (int p = 0; p < 192; p += 8){
    #pragma unroll
    for (int j = 0; j < 8; ++j)
      q[j] += ev[p+j]*bf2f(ep[(size_t)(p+j)*ENCD]);
  }
  #pragma unroll
  for (int j = 0; j < 4; ++j)
    q[j] += ev[192+j]*bf2f(ep[(size_t)(192+j)*ENCD]);
  float awe = (((q[0]+q[1])+(q[2]+q[3])) + ((q[4]+q[5])+(q[6]+q[7]))) / ssum;
  float gp = pA[(size_t)b*4608 + 512 + d] + bfb[d];
  float gate = 1.f/(1.f + expf(-gp));
  xa[(size_t)b*2048 + d] = f2bf(gate * awe);
  if (dc == 0 && tid < 196) out[O_ALPHA + ((size_t)b*64 + t)*196 + tid] = ev[tid]/ssum;
}

// ============ kC: gates GEMM (8-wave K-split) + LSTM fused ============
__global__ __launch_bounds__(512) void kC(const u16* __restrict__ xa,
    const u16* __restrict__ hc, u16* __restrict__ hn, float* __restrict__ c,
    const u16* __restrict__ WIH2, const float* __restrict__ pA,
    const float* __restrict__ bcomb, const u16* __restrict__ gemb,
    const int* __restrict__ len, int t){
  int tid = threadIdx.x, wv = tid>>6, lane = tid&63, lr = lane&15, lh = lane>>4;
  int jp0 = blockIdx.x*16;
  __shared__ float red[8*512];
  f32x4 acc0 = {0,0,0,0}, acc1 = {0,0,0,0};
  #pragma unroll
  for (int ks = 0; ks < 8; ++ks){
    int k = wv*256 + ks*32;
    bf16x8 a0 = *(const bf16x8*)&xa[(size_t)lr*2048 + k + lh*8];
    bf16x8 a1 = *(const bf16x8*)&xa[(size_t)(16+lr)*2048 + k + lh*8];
    bf16x8 bv = *(const bf16x8*)&WIH2[(size_t)(jp0+lr)*2048 + k + lh*8];
    acc0 = MF(a0, bv, acc0);
    acc1 = MF(a1, bv, acc1);
  }
  #pragma unroll
  for (int r = 0; r < 4; ++r){
    red[wv*512 + ((lh*4+r) << 4) + lr]    = acc0[r];
    red[wv*512 + ((16+lh*4+r) << 4) + lr] = acc1[r];
  }
  __syncthreads();
  {
    int b = tid >> 4, jl = tid & 15, e = jl & 3;
    int jp = jp0 + jl, u = jp >> 2;
    float g = 0.f;
    #pragma unroll
    for (int w = 0; w < 8; ++w) g += red[w*512 + tid];
    g += bcomb[jp] + bf2f(gemb[((size_t)b*64 + t)*2048 + jp])
       + pA[(size_t)b*4608 + 2560 + e*512 + u];
    float sv = (e == 2) ? tanhf(g) : 1.f/(1.f + expf(-g));
    float vb = __shfl_xor(sv, 1), vc = __shfl_xor(sv, 2), vd = __shfl_xor(vb, 2);
    float i_s = (e==0)?sv:(e==1)?vb:(e==2)?vc:vd;
    float f_s = (e==1)?sv:(e==0)?vb:(e==3)?vc:vd;
    float g_t = (e==2)?sv:(e==3)?vb:(e==0)?vc:vd;
    float o_s = (e==3)?sv:(e==2)?vb:(e==1)?vc:vd;
    float cold = c[(size_t)b*512 + u];
    float hold = bf2f(hc[(size_t)b*512 + u]);
    bool mk = t < len[b];
    float cn = mk ? (f_s*cold + i_s*g_t) : cold;
    float hv = mk ? (o_s * tanhf(cn)) : hold;
    if (e == 0){
      c[(size_t)b*512 + u] = cn;
      hn[(size_t)b*512 + u] = f2bf(hv);
    }
  }
}

// ================= host launcher =================
extern "C" void kernel_launch(void* const* d_in, const int* in_sizes, int n_in,
                              void* d_out, int out_size, void* d_ws, size_t ws_size,
                              hipStream_t stream){
  (void)in_sizes; (void)n_in; (void)out_size; (void)ws_size;
  const float* enc_out   = (const float*)d_in[0];
  const float* imgs      = (const float*)d_in[1];
  const int*   seq       = (const int*)d_in[2];
  const float* seqoff    = (const float*)d_in[3];
  const int*   caplen    = (const int*)d_in[4];
  const float* W_pe      = (const float*)d_in[5];
  const float* b_pe      = (const float*)d_in[6];
  const float* W_enc_att = (const float*)d_in[7];
  const float* b_enc_att = (const float*)d_in[8];
  const float* W_dec_att = (const float*)d_in[9];
  const float* b_dec_att = (const float*)d_in[10];
  const float* w_full    = (const float*)d_in[11];
  const float* b_full    = (const float*)d_in[12];
  const float* W_init_h  = (const float*)d_in[13];
  const float* b_init_h  = (const float*)d_in[14];
  const float* W_init_c  = (const float*)d_in[15];
  const float* b_init_c  = (const float*)d_in[16];
  const float* W_fb      = (const float*)d_in[17];
  const float* b_fb      = (const float*)d_in[18];
  const float* W_ih      = (const float*)d_in[19];
  const float* b_ih      = (const float*)d_in[20];
  const float* W_hh      = (const float*)d_in[21];
  const float* b_hh      = (const float*)d_in[22];
  const float* W_fc      = (const float*)d_in[23];
  const float* b_fc      = (const float*)d_in[24];
  const float* W_stop    = (const float*)d_in[25];
  const float* b_stop    = (const float*)d_in[26];

  float* out = (float*)d_out;
  float* ws  = (float*)d_ws;
  int*   wsi = (int*)d_ws;
  u16*   us  = (u16*)d_ws;

  u16* H[2] = { us + US_H0, us + US_H1 };

  k_prep<<<1, 64, 0, stream>>>(caplen, wsi + WS_SORT, wsi + WS_LEN, out);
  k_seqoff<<<16, 256, 0, stream>>>(seqoff, wsi + WS_SORT, out);
  k_encbf<<<6272, 256, 0, stream>>>(enc_out, wsi + WS_SORT, us + US_ENC);
  k_encmean<<<256, 256, 0, stream>>>(us + US_ENC, ws + WS_ENCM);
  k_patch<<<2048, 256, 0, stream>>>(imgs, seq, wsi + WS_SORT, us + US_PATCH);
  k_wpeb<<<768, 256, 0, stream>>>(W_pe, us + US_WPEB);
  k_embedv3<<<128, 256, 0, stream>>>(us + US_PATCH, us + US_WPEB, b_pe,
                                     us + US_EMBBF, ws + WS_EMB0);
  k_cvt2<<<7240, 256, 0, stream>>>(W_ih, W_hh, W_dec_att, W_fb, W_fc, W_stop, W_enc_att,
                                   b_ih, b_hh,
                                   us + US_WIH2, us + US_WIHE, us + US_WAP,
                                   us + US_WEA, ws + WS_BCOMB);
  k_att1v4<<<392, 256, 0, stream>>>(us + US_ENC, us + US_WEA, b_enc_att, us + US_ATT1T);
  k_gemb<<<256, 256, 0, stream>>>(us + US_EMBBF, us + US_WIHE, us + US_GEMB);
  k_initv2<<<16, 256, 0, stream>>>(ws + WS_ENCM, ws + WS_EMB0, W_init_h, b_init_h,
                                   W_init_c, b_init_c, H[0], ws + WS_C);

  for (int t = 0; t < Tn; ++t){
    kAB<<<321, 256, 0, stream>>>(H[t & 1], us + US_WAP, ws + WS_PA, us + US_ATT1T,
                                 b_dec_att, w_full, ws + WS_SCP, b_fc, b_stop,
                                 wsi + WS_LEN, out, t);
    kB2<<<256, 256, 0, stream>>>(ws + WS_SCP, ws + WS_PA, us + US_ENC, b_full, b_fb,
                                 us + US_XA, wsi + WS_LEN, out, t);
    kC<<<128, 512, 0, stream>>>(us + US_XA, H[t & 1], H[(t + 1) & 1], ws + WS_C,
                                us + US_WIH2, ws + WS_PA, ws + WS_BCOMB, us + US_GEMB,
                                wsi + WS_LEN, t);
  }
  kAB<<<321, 256, 0, stream>>>(H[0], us + US_WAP, ws + WS_PA, us + US_ATT1T,
                               b_dec_att, w_full, ws + WS_SCP, b_fc, b_stop,
                               wsi + WS_LEN, out, 64);
}

// Round 14
// 1919.079 us; speedup vs baseline: 1.3376x; 1.0317x over previous
//
#include <hip/hip_runtime.h>

// ---------------- problem constants ----------------
#define Bn 32
#define Tn 64
#define Pn 196
#define ENCD 2048
#define DECD 512
#define XDIM 2304

typedef unsigned short u16;
typedef __attribute__((ext_vector_type(8))) short bf16x8;
typedef __attribute__((ext_vector_type(4))) float f32x4;

#define MF(a,b,c) __builtin_amdgcn_mfma_f32_16x16x32_bf16(a,b,c,0,0,0)

static __device__ __forceinline__ u16 f2bf(float f){
  unsigned int u = __float_as_uint(f);
  unsigned int r = u + 0x7FFFu + ((u >> 16) & 1u);
  return (u16)(r >> 16);
}
static __device__ __forceinline__ float bf2f(u16 u){
  return __uint_as_float(((unsigned int)u) << 16);
}

// ---------------- output offsets (floats) ----------------
#define O_PRED   0
#define O_STOP   4096
#define O_SEQOFF 6144
#define O_LEN    10240
#define O_ALPHA  10272
#define O_SORT   411680

// ---------------- ws: f32/int region (f32 indices) ----------------
#define WS_SORT    0        // int[32]
#define WS_LEN     32       // int[32]
#define WS_C       64       // f32 [32][512]
#define WS_PA      16448    // f32 [32][4608] (also init partials [4][32][1024] pre-loop)
#define WS_SCP     163904   // f32 [32][8][200] score partials
#define WS_ENCM    215104   // f32 [32][2048]
#define WS_EMB0    280640   // f32 [32][256]
#define WS_BCOMB   288832   // f32 [2048]
// ---------------- ws: u16 region (absolute u16 indices from (u16*)d_ws) ----------------
#define US_H0      800000                 // [32][512]
#define US_H1      816384                 // [32][512]
#define US_XA      832768                 // [32][2048]
#define US_EMBBF   898304                 // [32][64][256]
#define US_ATT1T   1422592                // [32][512][208] transposed att1
#define US_ENC     4830464                // [6272][2048] sorted row-major
#define US_WAP     17675520               // [4672][512] Wdec|Wfb|Whh|Wfc(2)|Wstop|pad
#define US_WIHE    20067584               // [2048][256]  jp-interleaved
#define US_WIH2    20591872               // [2048][2048] jp-interleaved
#define US_GEMB    24786176               // [32*64][2048]
#define US_PATCH   20591872               // [2048][3072] ALIAS over WIH2+GEMB head (pre-cvt2)
#define US_WPEB    26883328               // [256][3072] bf16 W_pe — gap after PATCH, before WEA
#define US_WEA     27931904               // [512][2048]  ALIAS in GEMB tail (pre-gemb)

// ============ prep: stable descending sort ============
__global__ void k_prep(const int* __restrict__ caplen, int* __restrict__ ws_sort,
                       int* __restrict__ ws_len, float* __restrict__ out){
  __shared__ int len[32];
  int i = threadIdx.x;
  if (i < 32) len[i] = caplen[i];
  __syncthreads();
  if (i < 32){
    int li = len[i], r = 0;
    for (int j = 0; j < 32; j++){
      int lj = len[j];
      r += (lj > li) || (lj == li && j < i);
    }
    ws_sort[r] = i;
    ws_len[r]  = li;
    out[O_LEN + r]  = (float)li;
    out[O_SORT + r] = (float)i;
  }
}

__global__ void k_seqoff(const float* __restrict__ seqoff, const int* __restrict__ ws_sort,
                         float* __restrict__ out){
  int idx = blockIdx.x*256 + threadIdx.x;
  int b = idx >> 7, r = idx & 127;
  out[O_SEQOFF + idx] = seqoff[ws_sort[b]*128 + r];
}

// ============ enc -> sorted row-major bf16 [6272][2048] ============
__global__ void k_encbf(const float* __restrict__ enc, const int* __restrict__ srt,
                        u16* __restrict__ dst){
  int m = blockIdx.x;
  int b = m / 196, p = m - b*196;
  const float* src = enc + ((size_t)srt[b]*196 + p)*ENCD;
  u16* d = dst + (size_t)m*ENCD;
  int i = threadIdx.x*8;
  float4 v0 = *(const float4*)(src + i);
  float4 v1 = *(const float4*)(src + i + 4);
  bf16x8 s;
  s[0]=(short)f2bf(v0.x); s[1]=(short)f2bf(v0.y); s[2]=(short)f2bf(v0.z); s[3]=(short)f2bf(v0.w);
  s[4]=(short)f2bf(v1.x); s[5]=(short)f2bf(v1.y); s[6]=(short)f2bf(v1.z); s[7]=(short)f2bf(v1.w);
  *(bf16x8*)(d + i) = s;
}

__global__ void k_encmean(const u16* __restrict__ encbf, float* __restrict__ encm){
  int b = blockIdx.x >> 3, dc = blockIdx.x & 7;
  int d = dc*256 + threadIdx.x;
  const u16* ep = encbf + (size_t)(b*196)*ENCD + d;
  float s = 0.f;
  #pragma unroll 4
  for (int p = 0; p < Pn; p++) s += bf2f(ep[(size_t)p*ENCD]);
  encm[b*ENCD + d] = s * (1.f/196.f);
}

// ============ patch extraction -> bf16 ============
__global__ void k_patch(const float* __restrict__ imgs, const int* __restrict__ seq,
                        const int* __restrict__ srt, u16* __restrict__ patches){
  int blk = blockIdx.x; int b = blk>>6, t = blk&63;
  int sb = srt[b];
  int x0 = seq[(sb*64+t)*2 + 0], y0 = seq[(sb*64+t)*2 + 1];
  const float* img = imgs + (size_t)sb*3*512*512;
  u16* dst = patches + (size_t)(b*64+t)*3072;
  for (int idx = threadIdx.x; idx < 3072; idx += 256){
    int c = idx>>10, rem = idx&1023, i = rem>>5, j = rem&31;
    int yy = y0 + i - 24, xx = x0 + j - 24;
    float v = 0.f;
    if ((unsigned)yy < 512u && (unsigned)xx < 512u) v = img[((size_t)c*512 + yy)*512 + xx];
    dst[idx] = f2bf(v);
  }
}

// ============ embed GEMM v3 (all-bf16 MFMA) ============
__global__ __launch_bounds__(256) void k_embedv3(const u16* __restrict__ patches,
    const u16* __restrict__ wpeb, const float* __restrict__ b_pe,
    u16* __restrict__ embbf, float* __restrict__ emb0){
  int mb = blockIdx.x >> 2, nb = blockIdx.x & 3;
  int m0 = mb*64;
  __shared__ u16 A[64*136];
  int tid = threadIdx.x, wv = tid>>6, lane = tid&63, lr = lane&15, lh = lane>>4;
  f32x4 acc[4];
  #pragma unroll
  for (int mt = 0; mt < 4; mt++) acc[mt] = (f32x4){0,0,0,0};
  for (int kc = 0; kc < 24; kc++){
    __syncthreads();
    {
      int row = tid>>2, seg = tid&3;
      const u16* src = patches + (size_t)(m0 + row)*3072 + kc*128 + seg*32;
      #pragma unroll
      for (int i = 0; i < 4; i++)
        *(bf16x8*)&A[row*136 + seg*32 + i*8] = *(const bf16x8*)(src + i*8);
    }
    __syncthreads();
    #pragma unroll
    for (int ki = 0; ki < 4; ki++){
      bf16x8 bv = *(const bf16x8*)&wpeb[(size_t)(nb*64 + wv*16 + lr)*3072 + kc*128 + ki*32 + lh*8];
      #pragma unroll
      for (int mt = 0; mt < 4; mt++){
        bf16x8 av = *(const bf16x8*)&A[(mt*16 + lr)*136 + ki*32 + lh*8];
        acc[mt] = MF(av, bv, acc[mt]);
      }
    }
  }
  int n = nb*64 + wv*16 + lr;
  float bias = b_pe[n];
  #pragma unroll
  for (int mt = 0; mt < 4; mt++){
    #pragma unroll
    for (int r = 0; r < 4; r++){
      int t = mt*16 + lh*4 + r;
      float val = acc[mt][r] + bias;
      embbf[(size_t)(m0 + t)*256 + n] = f2bf(val);
      if (t == 0) emb0[mb*256 + n] = val;
    }
  }
}

// ============ weight converts (incl. W_pe) ============
__global__ void k_cvt2(const float* __restrict__ Wih, const float* __restrict__ Whh,
    const float* __restrict__ Wdec, const float* __restrict__ Wfb,
    const float* __restrict__ Wfc, const float* __restrict__ Wstop,
    const float* __restrict__ Wea, const float* __restrict__ W_pe,
    const float* __restrict__ bih, const float* __restrict__ bhh,
    u16* __restrict__ WIH2, u16* __restrict__ WIHE,
    u16* __restrict__ WAP, u16* __restrict__ WEAd, u16* __restrict__ wpeb,
    float* __restrict__ bcomb){
  int blk = blockIdx.x, tid = threadIdx.x;
  if (blk < 2048){
    int r = blk, jp = (r & 511)*4 + (r >> 9);
    for (int i = tid; i < 2304; i += 256){
      u16 v = f2bf(Wih[(size_t)r*2304 + i]);
      if (i < 2048) WIH2[(size_t)jp*2048 + i] = v;
      else          WIHE[(size_t)jp*256 + (i - 2048)] = v;
    }
  } else if (blk < 6720){
    int j = blk - 2048;
    const float* src;
    if (j < 512)        src = Wdec + (size_t)j*512;
    else if (j < 2560)  src = Wfb + (size_t)(j-512)*512;
    else if (j < 4608)  src = Whh + (size_t)(j-2560)*512;
    else if (j == 4608) src = Wfc;
    else if (j == 4609) src = Wfc + 512;
    else if (j == 4610) src = Wstop;
    else src = 0;
    for (int i = tid; i < 512; i += 256)
      WAP[(size_t)j*512 + i] = src ? f2bf(src[i]) : (u16)0;
  } else if (blk < 7232){
    int r = blk - 6720;
    for (int i = tid; i < 2048; i += 256)
      WEAd[(size_t)r*2048 + i] = f2bf(Wea[(size_t)r*2048 + i]);
  } else if (blk < 7240){
    int jp = (blk - 7232)*256 + tid;
    int r = (jp & 3)*512 + (jp >> 2);
    bcomb[jp] = bih[r] + bhh[r];
  } else {
    int i = ((blk - 7240)*256 + tid)*4;
    float4 v = *(const float4*)(W_pe + i);
    wpeb[i+0] = f2bf(v.x); wpeb[i+1] = f2bf(v.y);
    wpeb[i+2] = f2bf(v.z); wpeb[i+3] = f2bf(v.w);
  }
}

// ============ G_emb = emb @ WIHE^T ============
__global__ __launch_bounds__(256) void k_gemb(const u16* __restrict__ embbf,
    const u16* __restrict__ WIHE, u16* __restrict__ gemb){
  int m0 = (blockIdx.x >> 3)*64, n0 = (blockIdx.x & 7)*256;
  __shared__ u16 A[64*264];
  int tid = threadIdx.x, wv = tid>>6, lane = tid&63, lr = lane&15, lh = lane>>4;
  {
    int row = tid>>2, seg = tid&3;
    const u16* src = embbf + (size_t)(m0 + row)*256 + seg*64;
    #pragma unroll
    for (int i = 0; i < 8; i++)
      *(bf16x8*)&A[row*264 + seg*64 + i*8] = *(const bf16x8*)(src + i*8);
  }
  __syncthreads();
  f32x4 acc[4][4];
  #pragma unroll
  for (int mt = 0; mt < 4; mt++)
    #pragma unroll
    for (int nt = 0; nt < 4; nt++) acc[mt][nt] = (f32x4){0,0,0,0};
  #pragma unroll
  for (int ki = 0; ki < 8; ki++){
    bf16x8 av[4];
    #pragma unroll
    for (int mt = 0; mt < 4; mt++)
      av[mt] = *(const bf16x8*)&A[(mt*16 + lr)*264 + ki*32 + lh*8];
    #pragma unroll
    for (int nt = 0; nt < 4; nt++){
      bf16x8 bv = *(const bf16x8*)&WIHE[(size_t)(n0 + wv*64 + nt*16 + lr)*256 + ki*32 + lh*8];
      #pragma unroll
      for (int mt = 0; mt < 4; mt++) acc[mt][nt] = MF(av[mt], bv, acc[mt][nt]);
    }
  }
  #pragma unroll
  for (int nt = 0; nt < 4; nt++){
    int n = n0 + wv*64 + nt*16 + lr;
    #pragma unroll
    for (int mt = 0; mt < 4; mt++)
      #pragma unroll
      for (int r = 0; r < 4; r++)
        gemb[(size_t)(m0 + mt*16 + lh*4 + r)*2048 + n] = f2bf(acc[mt][nt][r]);
  }
}

// ============ att1 v4 -> TRANSPOSED att1T[b][512][208] ============
__global__ __launch_bounds__(256) void k_att1v4(const u16* __restrict__ encbf,
    const u16* __restrict__ Wea, const float* __restrict__ bea, u16* __restrict__ att1T){
  int mb = blockIdx.x >> 2, nb = blockIdx.x & 3;
  int m0 = mb*64;
  __shared__ u16 A[64*136];
  int tid = threadIdx.x, wv = tid>>6, lane = tid&63, lr = lane&15, lh = lane>>4;
  f32x4 acc[4][2];
  #pragma unroll
  for (int mt = 0; mt < 4; mt++){ acc[mt][0] = (f32x4){0,0,0,0}; acc[mt][1] = (f32x4){0,0,0,0}; }
  for (int kc = 0; kc < 16; kc++){
    __syncthreads();
    {
      int row = tid>>2, seg = tid&3;
      const u16* src = encbf + (size_t)(m0 + row)*2048 + kc*128 + seg*32;
      #pragma unroll
      for (int i = 0; i < 4; i++)
        *(bf16x8*)&A[row*136 + seg*32 + i*8] = *(const bf16x8*)(src + i*8);
    }
    __syncthreads();
    #pragma unroll
    for (int ki = 0; ki < 4; ki++){
      bf16x8 av[4];
      #pragma unroll
      for (int mt = 0; mt < 4; mt++)
        av[mt] = *(const bf16x8*)&A[(mt*16 + lr)*136 + ki*32 + lh*8];
      #pragma unroll
      for (int nt = 0; nt < 2; nt++){
        const u16* wp = Wea + (size_t)(nb*128 + wv*32 + nt*16 + lr)*2048 + kc*128 + ki*32 + lh*8;
        bf16x8 bv = *(const bf16x8*)wp;
        #pragma unroll
        for (int mt = 0; mt < 4; mt++) acc[mt][nt] = MF(av[mt], bv, acc[mt][nt]);
      }
    }
  }
  #pragma unroll
  for (int nt = 0; nt < 2; nt++){
    int n = nb*128 + wv*32 + nt*16 + lr;
    float bias = bea[n];
    #pragma unroll
    for (int mt = 0; mt < 4; mt++){
      #pragma unroll
      for (int r = 0; r < 4; r++){
        int m = m0 + mt*16 + lh*4 + r;
        int bb = m / 196, pp = m - bb*196;
        att1T[((size_t)bb*512 + n)*208 + pp] = f2bf(acc[mt][nt][r] + bias);
      }
    }
  }
}

// ============ h,c init v3: K-split MFMA partials ============
// grid 64 = 4 kc(576 K) x 16 jb(64 j); partials -> part[kc][b][j] (f32, in WS_PA)
__global__ __launch_bounds__(256) void k_initv3(const float* __restrict__ encm,
    const float* __restrict__ emb0,
    const float* __restrict__ Wh, const float* __restrict__ Wc,
    float* __restrict__ part){
  int kc = blockIdx.x >> 4, jb = blockIdx.x & 15;
  int tid = threadIdx.x, wv = tid>>6, lane = tid&63, lr = lane&15, lh = lane>>4;
  int j = jb*64 + wv*16 + lr;     // 0..1023
  const float* wbase = (j < 512) ? (Wh + (size_t)j*XDIM) : (Wc + (size_t)(j-512)*XDIM);
  f32x4 acc0 = {0,0,0,0}, acc1 = {0,0,0,0};
  #pragma unroll 2
  for (int kk = 0; kk < 576; kk += 32){
    int k = kc*576 + kk + lh*8;
    float4 w0 = *(const float4*)(wbase + k);
    float4 w1 = *(const float4*)(wbase + k + 4);
    bf16x8 bv;
    bv[0]=(short)f2bf(w0.x); bv[1]=(short)f2bf(w0.y); bv[2]=(short)f2bf(w0.z); bv[3]=(short)f2bf(w0.w);
    bv[4]=(short)f2bf(w1.x); bv[5]=(short)f2bf(w1.y); bv[6]=(short)f2bf(w1.z); bv[7]=(short)f2bf(w1.w);
    float4 x0, x1, y0, y1;
    if (k < 2048){
      x0 = *(const float4*)(encm + (size_t)lr*2048 + k);
      x1 = *(const float4*)(encm + (size_t)lr*2048 + k + 4);
      y0 = *(const float4*)(encm + (size_t)(16+lr)*2048 + k);
      y1 = *(const float4*)(encm + (size_t)(16+lr)*2048 + k + 4);
    } else {
      int ke = k - 2048;
      x0 = *(const float4*)(emb0 + (size_t)lr*256 + ke);
      x1 = *(const float4*)(emb0 + (size_t)lr*256 + ke + 4);
      y0 = *(const float4*)(emb0 + (size_t)(16+lr)*256 + ke);
      y1 = *(const float4*)(emb0 + (size_t)(16+lr)*256 + ke + 4);
    }
    bf16x8 a0, a1;
    a0[0]=(short)f2bf(x0.x); a0[1]=(short)f2bf(x0.y); a0[2]=(short)f2bf(x0.z); a0[3]=(short)f2bf(x0.w);
    a0[4]=(short)f2bf(x1.x); a0[5]=(short)f2bf(x1.y); a0[6]=(short)f2bf(x1.z); a0[7]=(short)f2bf(x1.w);
    a1[0]=(short)f2bf(y0.x); a1[1]=(short)f2bf(y0.y); a1[2]=(short)f2bf(y0.z); a1[3]=(short)f2bf(y0.w);
    a1[4]=(short)f2bf(y1.x); a1[5]=(short)f2bf(y1.y); a1[6]=(short)f2bf(y1.z); a1[7]=(short)f2bf(y1.w);
    acc0 = MF(a0, bv, acc0);
    acc1 = MF(a1, bv, acc1);
  }
  #pragma unroll
  for (int r = 0; r < 4; ++r){
    int b0 = lh*4 + r, b1 = 16 + b0;
    part[(size_t)(kc*32 + b0)*1024 + j] = acc0[r];
    part[(size_t)(kc*32 + b1)*1024 + j] = acc1[r];
  }
}

// reduce: sum 4 K-partials + bias -> h_bf / c
__global__ __launch_bounds__(256) void k_initv3r(const float* __restrict__ part,
    const float* __restrict__ bh, const float* __restrict__ bc,
    u16* __restrict__ h_bf, float* __restrict__ c){
  int idx = blockIdx.x*256 + threadIdx.x;   // 0..32767
  int b = idx >> 10, j = idx & 1023;
  float s = part[(size_t)b*1024 + j] + part[(size_t)(32+b)*1024 + j]
          + part[(size_t)(64+b)*1024 + j] + part[(size_t)(96+b)*1024 + j];
  if (j < 512) h_bf[(size_t)b*512 + j] = f2bf(s + bh[j]);
  else         c[(size_t)b*512 + (j-512)] = s + bc[j-512];
}

// ============ kAB: fused [kA: pA rows 512..4607 + preds] and [kB1: att2 local + score partials] ============
__global__ __launch_bounds__(256) void kAB(const u16* __restrict__ h, const u16* __restrict__ WAP,
    float* __restrict__ pA, const u16* __restrict__ att1T,
    const float* __restrict__ bdec, const float* __restrict__ wfull,
    float* __restrict__ scp, const float* __restrict__ bfc, const float* __restrict__ bstop,
    const int* __restrict__ len, float* __restrict__ out, int t){
  int blk = blockIdx.x, tid = threadIdx.x;
  if (t == 64 && blk != 64) return;      // final call: preds block only
  if (blk < 65){
    __shared__ u16 HL[32*520];
    int wv = tid>>6, lane = tid&63, lr = lane&15, lh = lane>>4;
    for (int i = tid; i < 4096; i += 256){
      unsigned long long v = ((const unsigned long long*)h)[i];
      int row = i >> 7, col = (i & 127)*4;
      *(unsigned long long*)&HL[row*520 + col] = v;
    }
    __syncthreads();
    int j0 = 512 + blk*64 + wv*16;
    f32x4 acc0 = {0,0,0,0}, acc1 = {0,0,0,0};
    #pragma unroll 4
    for (int ki = 0; ki < 16; ++ki){
      bf16x8 bv = *(const bf16x8*)&WAP[(size_t)(j0+lr)*512 + ki*32 + lh*8];
      bf16x8 a0 = *(const bf16x8*)&HL[lr*520 + ki*32 + lh*8];
      bf16x8 a1 = *(const bf16x8*)&HL[(16+lr)*520 + ki*32 + lh*8];
      acc0 = MF(a0, bv, acc0);
      acc1 = MF(a1, bv, acc1);
    }
    int j = j0 + lr;
    if (j < 4608){
      #pragma unroll
      for (int r = 0; r < 4; ++r){
        pA[(size_t)(lh*4+r)*4608 + j]    = acc0[r];
        pA[(size_t)(lh*4+r+16)*4608 + j] = acc1[r];
      }
    } else if (j < 4611 && t > 0){
      int jj = j - 4608, tm1 = t - 1;
      #pragma unroll
      for (int r = 0; r < 4; ++r){
        #pragma unroll
        for (int hb = 0; hb < 2; ++hb){
          int b0 = lh*4 + r + hb*16;
          float val = hb ? acc1[r] : acc0[r];
          bool mk = tm1 < len[b0];
          if (jj < 2) out[O_PRED + ((size_t)b0*64 + tm1)*2 + jj] = mk ? val + bfc[jj] : 0.f;
          else        out[O_STOP + (size_t)b0*64 + tm1] =
                        mk ? 1.f/(1.f + expf(-(val + bstop[0]))) : 0.f;
        }
      }
    }
  } else {
    int kb = blk - 65, b = kb >> 3, ac = kb & 7;
    if (t >= len[b]) return;
    __shared__ u16 hL[512];
    __shared__ float a2s[64], wfs[64];
    if (tid < 128)
      ((unsigned long long*)hL)[tid] = ((const unsigned long long*)(h + (size_t)b*512))[tid];
    if (tid < 64) wfs[tid] = wfull[ac*64 + tid];
    __syncthreads();
    {
      int a = tid >> 2, q = tid & 3;
      const u16* wrow = WAP + (size_t)(ac*64 + a)*512 + q*128;
      const u16* hrow = hL + q*128;
      float acc = 0.f;
      #pragma unroll
      for (int i = 0; i < 16; ++i){
        bf16x8 wv8 = *(const bf16x8*)(wrow + i*8);
        bf16x8 hv8 = *(const bf16x8*)(hrow + i*8);
        #pragma unroll
        for (int e = 0; e < 8; ++e) acc += bf2f((u16)hv8[e]) * bf2f((u16)wv8[e]);
      }
      acc += __shfl_xor(acc, 1);
      acc += __shfl_xor(acc, 2);
      if (q == 0) a2s[a] = acc + bdec[ac*64 + a];
    }
    __syncthreads();
    int p = tid;
    if (p < 196){
      const u16* col = att1T + ((size_t)b*512 + ac*64)*208 + p;
      float acc = 0.f;
      #pragma unroll 8
      for (int a = 0; a < 64; ++a)
        acc += fmaxf(bf2f(col[(size_t)a*208]) + a2s[a], 0.f) * wfs[a];
      scp[(size_t)(b*8 + ac)*200 + p] = acc;
    }
  }
}

// ============ kB2: softmax + awe + gate -> xa ; alphas ============
__global__ __launch_bounds__(256) void kB2(const float* __restrict__ scp,
    const float* __restrict__ pA, const u16* __restrict__ encbf,
    const float* __restrict__ bfull, const float* __restrict__ bfb,
    u16* __restrict__ xa, const int* __restrict__ len, float* __restrict__ out, int t){
  int b = blockIdx.x >> 3, dc = blockIdx.x & 7;
  int tid = threadIdx.x, wv = tid>>6, lane = tid&63;
  if (t >= len[b]){
    if (dc == 0 && tid < 196) out[O_ALPHA + ((size_t)b*64 + t)*196 + tid] = 0.f;
    return;
  }
  __shared__ float ev[200], redf[4], bcx[2];
  float s = -1e30f;
  if (tid < 196){
    s = bfull[0];
    #pragma unroll
    for (int q = 0; q < 8; ++q) s += scp[(size_t)(b*8 + q)*200 + tid];
  }
  float m = s;
  #pragma unroll
  for (int o = 32; o; o >>= 1) m = fmaxf(m, __shfl_down(m, o));
  if (lane == 0) redf[wv] = m;
  __syncthreads();
  if (tid == 0) bcx[0] = fmaxf(fmaxf(redf[0],redf[1]), fmaxf(redf[2],redf[3]));
  __syncthreads();
  float e = (tid < 196) ? expf(s - bcx[0]) : 0.f;
  if (tid < 200) ev[tid] = (tid < 196) ? e : 0.f;
  float sm = e;
  #pragma unroll
  for (int o = 32; o; o >>= 1) sm += __shfl_down(sm, o);
  __syncthreads();
  if (lane == 0) redf[wv] = sm;
  __syncthreads();
  if (tid == 0) bcx[1] = redf[0]+redf[1]+redf[2]+redf[3];
  __syncthreads();
  float ssum = bcx[1];
  int d = dc*256 + tid;
  const u16* ep = encbf + (size_t)(b*196)*ENCD + d;
  float q[8];
  #pragma unroll
  for (int j = 0; j < 8; ++j) q[j] = 0.f;
  #pragma unroll 2
  for (int p = 0; p < 192; p += 8){
    #pragma unroll
    for (int j = 0; j < 8; ++j)
      q[j] += ev[p+j]*bf2f(ep[(size_t)(p+j)*ENCD]);
  }
  #pragma unroll
  for (int j = 0; j < 4; ++j)
    q[j] += ev[192+j]*bf2f(ep[(size_t)(192+j)*ENCD]);
  float awe = (((q[0]+q[1])+(q[2]+q[3])) + ((q[4]+q[5])+(q[6]+q[7]))) / ssum;
  float gp = pA[(size_t)b*4608 + 512 + d] + bfb[d];
  float gate = 1.f/(1.f + expf(-gp));
  xa[(size_t)b*2048 + d] = f2bf(gate * awe);
  if (dc == 0 && tid < 196) out[O_ALPHA + ((size_t)b*64 + t)*196 + tid] = ev[tid]/ssum;
}

// ============ kC: gates GEMM (8-wave K-split) + LSTM fused ============
__global__ __launch_bounds__(512) void kC(const u16* __restrict__ xa,
    const u16* __restrict__ hc, u16* __restrict__ hn, float* __restrict__ c,
    const u16* __restrict__ WIH2, const float* __restrict__ pA,
    const float* __restrict__ bcomb, const u16* __restrict__ gemb,
    const int* __restrict__ len, int t){
  int tid = threadIdx.x, wv = tid>>6, lane = tid&63, lr = lane&15, lh = lane>>4;
  int jp0 = blockIdx.x*16;
  __shared__ float red[8*512];
  f32x4 acc0 = {0,0,0,0}, acc1 = {0,0,0,0};
  #pragma unroll
  for (int ks = 0; ks < 8; ++ks){
    int k = wv*256 + ks*32;
    bf16x8 a0 = *(const bf16x8*)&xa[(size_t)lr*2048 + k + lh*8];
    bf16x8 a1 = *(const bf16x8*)&xa[(size_t)(16+lr)*2048 + k + lh*8];
    bf16x8 bv = *(const bf16x8*)&WIH2[(size_t)(jp0+lr)*2048 + k + lh*8];
    acc0 = MF(a0, bv, acc0);
    acc1 = MF(a1, bv, acc1);
  }
  #pragma unroll
  for (int r = 0; r < 4; ++r){
    red[wv*512 + ((lh*4+r) << 4) + lr]    = acc0[r];
    red[wv*512 + ((16+lh*4+r) << 4) + lr] = acc1[r];
  }
  __syncthreads();
  {
    int b = tid >> 4, jl = tid & 15, e = jl & 3;
    int jp = jp0 + jl, u = jp >> 2;
    float g = 0.f;
    #pragma unroll
    for (int w = 0; w < 8; ++w) g += red[w*512 + tid];
    g += bcomb[jp] + bf2f(gemb[((size_t)b*64 + t)*2048 + jp])
       + pA[(size_t)b*4608 + 2560 + e*512 + u];
    float sv = (e == 2) ? tanhf(g) : 1.f/(1.f + expf(-g));
    float vb = __shfl_xor(sv, 1), vc = __shfl_xor(sv, 2), vd = __shfl_xor(vb, 2);
    float i_s = (e==0)?sv:(e==1)?vb:(e==2)?vc:vd;
    float f_s = (e==1)?sv:(e==0)?vb:(e==3)?vc:vd;
    float g_t = (e==2)?sv:(e==3)?vb:(e==0)?vc:vd;
    float o_s = (e==3)?sv:(e==2)?vb:(e==1)?vc:vd;
    float cold = c[(size_t)b*512 + u];
    float hold = bf2f(hc[(size_t)b*512 + u]);
    bool mk = t < len[b];
    float cn = mk ? (f_s*cold + i_s*g_t) : cold;
    float hv = mk ? (o_s * tanhf(cn)) : hold;
    if (e == 0){
      c[(size_t)b*512 + u] = cn;
      hn[(size_t)b*512 + u] = f2bf(hv);
    }
  }
}

// ================= host launcher =================
extern "C" void kernel_launch(void* const* d_in, const int* in_sizes, int n_in,
                              void* d_out, int out_size, void* d_ws, size_t ws_size,
                              hipStream_t stream){
  (void)in_sizes; (void)n_in; (void)out_size; (void)ws_size;
  const float* enc_out   = (const float*)d_in[0];
  const float* imgs      = (const float*)d_in[1];
  const int*   seq       = (const int*)d_in[2];
  const float* seqoff    = (const float*)d_in[3];
  const int*   caplen    = (const int*)d_in[4];
  const float* W_pe      = (const float*)d_in[5];
  const float* b_pe      = (const float*)d_in[6];
  const float* W_enc_att = (const float*)d_in[7];
  const float* b_enc_att = (const float*)d_in[8];
  const float* W_dec_att = (const float*)d_in[9];
  const float* b_dec_att = (const float*)d_in[10];
  const float* w_full    = (const float*)d_in[11];
  const float* b_full    = (const float*)d_in[12];
  const float* W_init_h  = (const float*)d_in[13];
  const float* b_init_h  = (const float*)d_in[14];
  const float* W_init_c  = (const float*)d_in[15];
  const float* b_init_c  = (const float*)d_in[16];
  const float* W_fb      = (const float*)d_in[17];
  const float* b_fb      = (const float*)d_in[18];
  const float* W_ih      = (const float*)d_in[19];
  const float* b_ih      = (const float*)d_in[20];
  const float* W_hh      = (const float*)d_in[21];
  const float* b_hh      = (const float*)d_in[22];
  const float* W_fc      = (const float*)d_in[23];
  const float* b_fc      = (const float*)d_in[24];
  const float* W_stop    = (const float*)d_in[25];
  const float* b_stop    = (const float*)d_in[26];

  float* out = (float*)d_out;
  float* ws  = (float*)d_ws;
  int*   wsi = (int*)d_ws;
  u16*   us  = (u16*)d_ws;

  u16* H[2] = { us + US_H0, us + US_H1 };

  k_prep<<<1, 64, 0, stream>>>(caplen, wsi + WS_SORT, wsi + WS_LEN, out);
  k_seqoff<<<16, 256, 0, stream>>>(seqoff, wsi + WS_SORT, out);
  k_encbf<<<6272, 256, 0, stream>>>(enc_out, wsi + WS_SORT, us + US_ENC);
  k_encmean<<<256, 256, 0, stream>>>(us + US_ENC, ws + WS_ENCM);
  k_patch<<<2048, 256, 0, stream>>>(imgs, seq, wsi + WS_SORT, us + US_PATCH);
  k_cvt2<<<8008, 256, 0, stream>>>(W_ih, W_hh, W_dec_att, W_fb, W_fc, W_stop, W_enc_att, W_pe,
                                   b_ih, b_hh,
                                   us + US_WIH2, us + US_WIHE, us + US_WAP,
                                   us + US_WEA, us + US_WPEB, ws + WS_BCOMB);
  k_embedv3<<<128, 256, 0, stream>>>(us + US_PATCH, us + US_WPEB, b_pe,
                                     us + US_EMBBF, ws + WS_EMB0);
  k_att1v4<<<392, 256, 0, stream>>>(us + US_ENC, us + US_WEA, b_enc_att, us + US_ATT1T);
  k_gemb<<<256, 256, 0, stream>>>(us + US_EMBBF, us + US_WIHE, us + US_GEMB);
  k_initv3<<<64, 256, 0, stream>>>(ws + WS_ENCM, ws + WS_EMB0, W_init_h, W_init_c, ws + WS_PA);
  k_initv3r<<<128, 256, 0, stream>>>(ws + WS_PA, b_init_h, b_init_c, H[0], ws + WS_C);

  for (int t = 0; t < Tn; ++t){
    kAB<<<321, 256, 0, stream>>>(H[t & 1], us + US_WAP, ws + WS_PA, us + US_ATT1T,
                                 b_dec_att, w_full, ws + WS_SCP, b_fc, b_stop,
                                 wsi + WS_LEN, out, t);
    kB2<<<256, 256, 0, stream>>>(ws + WS_SCP, ws + WS_PA, us + US_ENC, b_full, b_fb,
                                 us + US_XA, wsi + WS_LEN, out, t);
    kC<<<128, 512, 0, stream>>>(us + US_XA, H[t & 1], H[(t + 1) & 1], ws + WS_C,
                                us + US_WIH2, ws + WS_PA, ws + WS_BCOMB, us + US_GEMB,
                                wsi + WS_LEN, t);
  }
  kAB<<<321, 256, 0, stream>>>(H[0], us + US_WAP, ws + WS_PA, us + US_ATT1T,
                               b_dec_att, w_full, ws + WS_SCP, b_fc, b_stop,
                               wsi + WS_LEN, out, 64);
}

// Round 15
// 1904.498 us; speedup vs baseline: 1.3479x; 1.0077x over previous
//
#include <hip/hip_runtime.h>

// ---------------- problem constants ----------------
#define Bn 32
#define Tn 64
#define Pn 196
#define ENCD 2048
#define DECD 512
#define XDIM 2304

typedef unsigned short u16;
typedef __attribute__((ext_vector_type(8))) short bf16x8;
typedef __attribute__((ext_vector_type(4))) float f32x4;

#define MF(a,b,c) __builtin_amdgcn_mfma_f32_16x16x32_bf16(a,b,c,0,0,0)

static __device__ __forceinline__ u16 f2bf(float f){
  unsigned int u = __float_as_uint(f);
  unsigned int r = u + 0x7FFFu + ((u >> 16) & 1u);
  return (u16)(r >> 16);
}
static __device__ __forceinline__ float bf2f(u16 u){
  return __uint_as_float(((unsigned int)u) << 16);
}

// ---------------- output offsets (floats) ----------------
#define O_PRED   0
#define O_STOP   4096
#define O_SEQOFF 6144
#define O_LEN    10240
#define O_ALPHA  10272
#define O_SORT   411680

// ---------------- ws: f32/int region (f32 indices) ----------------
#define WS_SORT    0        // int[32]
#define WS_LEN     32       // int[32]
#define WS_C       64       // f32 [32][512]
#define WS_PA      16448    // f32 [32][4608] (also init partials [4][32][1024] pre-loop)
#define WS_SCP     163904   // f32 [32][8][200] score partials
#define WS_ENCM    215104   // f32 [32][2048]
#define WS_EMB0    280640   // f32 [32][256]
#define WS_BCOMB   288832   // f32 [2048]
// ---------------- ws: u16 region (absolute u16 indices from (u16*)d_ws) ----------------
#define US_H0      800000                 // [32][512]
#define US_H1      816384                 // [32][512]
#define US_XA      832768                 // [32][2048]
#define US_EMBBF   898304                 // [32][64][256]
#define US_ATT1T   1422592                // [32][512][208] transposed att1
#define US_ENC     4830464                // [6272][2048] sorted row-major
#define US_WAP     17675520               // [4672][512] Wdec|Wfb|Whh|Wfc(2)|Wstop|pad
#define US_WIHE    20067584               // [2048][256]  jp-interleaved
#define US_WIH2    20591872               // [2048][2048] jp-interleaved (StageC; clobbers PATCH)
#define US_GEMB    24786176               // [32*64][2048] (StageD; clobbers PATCH tail/WPEB/WEA)
#define US_PATCH   20591872               // [2048][3072] ALIAS (StageA write, StageB read)
#define US_WPEB    26883328               // [256][3072] bf16 W_pe (StageA write, StageB read)
#define US_WEA     27931904               // [512][2048] bf16 W_enc_att (StageA write, StageB read)

// ============ prep: stable descending sort ============
__global__ void k_prep(const int* __restrict__ caplen, int* __restrict__ ws_sort,
                       int* __restrict__ ws_len, float* __restrict__ out){
  __shared__ int len[32];
  int i = threadIdx.x;
  if (i < 32) len[i] = caplen[i];
  __syncthreads();
  if (i < 32){
    int li = len[i], r = 0;
    for (int j = 0; j < 32; j++){
      int lj = len[j];
      r += (lj > li) || (lj == li && j < i);
    }
    ws_sort[r] = i;
    ws_len[r]  = li;
    out[O_LEN + r]  = (float)li;
    out[O_SORT + r] = (float)i;
  }
}

// ============ StageA: encbf | encmean(fp32) | patch | wpeb | wea | seqoff ============
// grid 9872 = 6272 encbf + 256 encmean + 2048 patch + 768 wpeb + 512 wea + 16 seqoff
__global__ __launch_bounds__(256) void k_stageA(const float* __restrict__ enc,
    const float* __restrict__ imgs, const int* __restrict__ seq,
    const float* __restrict__ W_pe, const float* __restrict__ Wea,
    const float* __restrict__ seqoff, const int* __restrict__ srt,
    u16* __restrict__ encbf, float* __restrict__ encm, u16* __restrict__ patches,
    u16* __restrict__ wpeb, u16* __restrict__ wead, float* __restrict__ out){
  int blk = blockIdx.x, tid = threadIdx.x;
  if (blk < 6272){
    int m = blk;
    int b = m / 196, p = m - b*196;
    const float* src = enc + ((size_t)srt[b]*196 + p)*ENCD;
    u16* d = encbf + (size_t)m*ENCD;
    int i = tid*8;
    float4 v0 = *(const float4*)(src + i);
    float4 v1 = *(const float4*)(src + i + 4);
    bf16x8 s;
    s[0]=(short)f2bf(v0.x); s[1]=(short)f2bf(v0.y); s[2]=(short)f2bf(v0.z); s[3]=(short)f2bf(v0.w);
    s[4]=(short)f2bf(v1.x); s[5]=(short)f2bf(v1.y); s[6]=(short)f2bf(v1.z); s[7]=(short)f2bf(v1.w);
    *(bf16x8*)(d + i) = s;
  } else if (blk < 6528){
    int r = blk - 6272;
    int b = r >> 3, dc = r & 7;
    int d = dc*256 + tid;
    const float* ep = enc + ((size_t)srt[b]*196)*ENCD + d;
    float s = 0.f;
    #pragma unroll 4
    for (int p = 0; p < Pn; p++) s += ep[(size_t)p*ENCD];
    encm[b*ENCD + d] = s * (1.f/196.f);
  } else if (blk < 8576){
    int r = blk - 6528;
    int b = r>>6, t = r&63;
    int sb = srt[b];
    int x0 = seq[(sb*64+t)*2 + 0], y0 = seq[(sb*64+t)*2 + 1];
    const float* img = imgs + (size_t)sb*3*512*512;
    u16* dst = patches + (size_t)(b*64+t)*3072;
    for (int idx = tid; idx < 3072; idx += 256){
      int c = idx>>10, rem = idx&1023, i = rem>>5, j = rem&31;
      int yy = y0 + i - 24, xx = x0 + j - 24;
      float v = 0.f;
      if ((unsigned)yy < 512u && (unsigned)xx < 512u) v = img[((size_t)c*512 + yy)*512 + xx];
      dst[idx] = f2bf(v);
    }
  } else if (blk < 9344){
    int i = ((blk - 8576)*256 + tid)*4;
    float4 v = *(const float4*)(W_pe + i);
    wpeb[i+0] = f2bf(v.x); wpeb[i+1] = f2bf(v.y);
    wpeb[i+2] = f2bf(v.z); wpeb[i+3] = f2bf(v.w);
  } else if (blk < 9856){
    int r = blk - 9344;
    for (int i = tid; i < 2048; i += 256)
      wead[(size_t)r*2048 + i] = f2bf(Wea[(size_t)r*2048 + i]);
  } else {
    int idx = (blk - 9856)*256 + tid;
    int b = idx >> 7, r = idx & 127;
    out[O_SEQOFF + idx] = seqoff[srt[b]*128 + r];
  }
}

// ============ StageB: embedv3 | att1v4 ============
// grid 520 = 128 embed + 392 att1
__global__ __launch_bounds__(256) void k_stageB(const u16* __restrict__ patches,
    const u16* __restrict__ wpeb, const float* __restrict__ b_pe,
    const u16* __restrict__ encbf, const u16* __restrict__ wead,
    const float* __restrict__ bea,
    u16* __restrict__ embbf, float* __restrict__ emb0, u16* __restrict__ att1T){
  __shared__ u16 A[64*136];
  int blk = blockIdx.x, tid = threadIdx.x;
  int wv = tid>>6, lane = tid&63, lr = lane&15, lh = lane>>4;
  if (blk < 128){
    int mb = blk >> 2, nb = blk & 3;
    int m0 = mb*64;
    f32x4 acc[4];
    #pragma unroll
    for (int mt = 0; mt < 4; mt++) acc[mt] = (f32x4){0,0,0,0};
    for (int kc = 0; kc < 24; kc++){
      __syncthreads();
      {
        int row = tid>>2, seg = tid&3;
        const u16* src = patches + (size_t)(m0 + row)*3072 + kc*128 + seg*32;
        #pragma unroll
        for (int i = 0; i < 4; i++)
          *(bf16x8*)&A[row*136 + seg*32 + i*8] = *(const bf16x8*)(src + i*8);
      }
      __syncthreads();
      #pragma unroll
      for (int ki = 0; ki < 4; ki++){
        bf16x8 bv = *(const bf16x8*)&wpeb[(size_t)(nb*64 + wv*16 + lr)*3072 + kc*128 + ki*32 + lh*8];
        #pragma unroll
        for (int mt = 0; mt < 4; mt++){
          bf16x8 av = *(const bf16x8*)&A[(mt*16 + lr)*136 + ki*32 + lh*8];
          acc[mt] = MF(av, bv, acc[mt]);
        }
      }
    }
    int n = nb*64 + wv*16 + lr;
    float bias = b_pe[n];
    #pragma unroll
    for (int mt = 0; mt < 4; mt++){
      #pragma unroll
      for (int r = 0; r < 4; r++){
        int t = mt*16 + lh*4 + r;
        float val = acc[mt][r] + bias;
        embbf[(size_t)(m0 + t)*256 + n] = f2bf(val);
        if (t == 0) emb0[mb*256 + n] = val;
      }
    }
  } else {
    int ab = blk - 128;
    int mb = ab >> 2, nb = ab & 3;
    int m0 = mb*64;
    f32x4 acc[4][2];
    #pragma unroll
    for (int mt = 0; mt < 4; mt++){ acc[mt][0] = (f32x4){0,0,0,0}; acc[mt][1] = (f32x4){0,0,0,0}; }
    for (int kc = 0; kc < 16; kc++){
      __syncthreads();
      {
        int row = tid>>2, seg = tid&3;
        const u16* src = encbf + (size_t)(m0 + row)*2048 + kc*128 + seg*32;
        #pragma unroll
        for (int i = 0; i < 4; i++)
          *(bf16x8*)&A[row*136 + seg*32 + i*8] = *(const bf16x8*)(src + i*8);
      }
      __syncthreads();
      #pragma unroll
      for (int ki = 0; ki < 4; ki++){
        bf16x8 av[4];
        #pragma unroll
        for (int mt = 0; mt < 4; mt++)
          av[mt] = *(const bf16x8*)&A[(mt*16 + lr)*136 + ki*32 + lh*8];
        #pragma unroll
        for (int nt = 0; nt < 2; nt++){
          const u16* wp = wead + (size_t)(nb*128 + wv*32 + nt*16 + lr)*2048 + kc*128 + ki*32 + lh*8;
          bf16x8 bv = *(const bf16x8*)wp;
          #pragma unroll
          for (int mt = 0; mt < 4; mt++) acc[mt][nt] = MF(av[mt], bv, acc[mt][nt]);
        }
      }
    }
    #pragma unroll
    for (int nt = 0; nt < 2; nt++){
      int n = nb*128 + wv*32 + nt*16 + lr;
      float bias = bea[n];
      #pragma unroll
      for (int mt = 0; mt < 4; mt++){
        #pragma unroll
        for (int r = 0; r < 4; r++){
          int m = m0 + mt*16 + lh*4 + r;
          int bb = m / 196, pp = m - bb*196;
          att1T[((size_t)bb*512 + n)*208 + pp] = f2bf(acc[mt][nt][r] + bias);
        }
      }
    }
  }
}

// ============ StageC: W_ih->WIH2/WIHE | WAP | bcomb | initv3 ============
// grid 6792 = 2048 wih + 4672 wap + 8 bcomb + 64 initv3
__global__ __launch_bounds__(256) void k_stageC(const float* __restrict__ Wih,
    const float* __restrict__ Whh, const float* __restrict__ Wdec,
    const float* __restrict__ Wfb, const float* __restrict__ Wfc,
    const float* __restrict__ Wstop, const float* __restrict__ bih,
    const float* __restrict__ bhh,
    const float* __restrict__ encm, const float* __restrict__ emb0,
    const float* __restrict__ Wh, const float* __restrict__ Wc,
    u16* __restrict__ WIH2, u16* __restrict__ WIHE, u16* __restrict__ WAP,
    float* __restrict__ bcomb, float* __restrict__ part){
  int blk = blockIdx.x, tid = threadIdx.x;
  if (blk < 2048){
    int r = blk, jp = (r & 511)*4 + (r >> 9);
    for (int i = tid; i < 2304; i += 256){
      u16 v = f2bf(Wih[(size_t)r*2304 + i]);
      if (i < 2048) WIH2[(size_t)jp*2048 + i] = v;
      else          WIHE[(size_t)jp*256 + (i - 2048)] = v;
    }
  } else if (blk < 6720){
    int j = blk - 2048;
    const float* src;
    if (j < 512)        src = Wdec + (size_t)j*512;
    else if (j < 2560)  src = Wfb + (size_t)(j-512)*512;
    else if (j < 4608)  src = Whh + (size_t)(j-2560)*512;
    else if (j == 4608) src = Wfc;
    else if (j == 4609) src = Wfc + 512;
    else if (j == 4610) src = Wstop;
    else src = 0;
    for (int i = tid; i < 512; i += 256)
      WAP[(size_t)j*512 + i] = src ? f2bf(src[i]) : (u16)0;
  } else if (blk < 6728){
    int jp = (blk - 6720)*256 + tid;
    int r = (jp & 3)*512 + (jp >> 2);
    bcomb[jp] = bih[r] + bhh[r];
  } else {
    int ib = blk - 6728;
    int kc = ib >> 4, jb = ib & 15;
    int wv = tid>>6, lane = tid&63, lr = lane&15, lh = lane>>4;
    int j = jb*64 + wv*16 + lr;
    const float* wbase = (j < 512) ? (Wh + (size_t)j*XDIM) : (Wc + (size_t)(j-512)*XDIM);
    f32x4 acc0 = {0,0,0,0}, acc1 = {0,0,0,0};
    #pragma unroll 2
    for (int kk = 0; kk < 576; kk += 32){
      int k = kc*576 + kk + lh*8;
      float4 w0 = *(const float4*)(wbase + k);
      float4 w1 = *(const float4*)(wbase + k + 4);
      bf16x8 bv;
      bv[0]=(short)f2bf(w0.x); bv[1]=(short)f2bf(w0.y); bv[2]=(short)f2bf(w0.z); bv[3]=(short)f2bf(w0.w);
      bv[4]=(short)f2bf(w1.x); bv[5]=(short)f2bf(w1.y); bv[6]=(short)f2bf(w1.z); bv[7]=(short)f2bf(w1.w);
      float4 x0, x1, y0, y1;
      if (k < 2048){
        x0 = *(const float4*)(encm + (size_t)lr*2048 + k);
        x1 = *(const float4*)(encm + (size_t)lr*2048 + k + 4);
        y0 = *(const float4*)(encm + (size_t)(16+lr)*2048 + k);
        y1 = *(const float4*)(encm + (size_t)(16+lr)*2048 + k + 4);
      } else {
        int ke = k - 2048;
        x0 = *(const float4*)(emb0 + (size_t)lr*256 + ke);
        x1 = *(const float4*)(emb0 + (size_t)lr*256 + ke + 4);
        y0 = *(const float4*)(emb0 + (size_t)(16+lr)*256 + ke);
        y1 = *(const float4*)(emb0 + (size_t)(16+lr)*256 + ke + 4);
      }
      bf16x8 a0, a1;
      a0[0]=(short)f2bf(x0.x); a0[1]=(short)f2bf(x0.y); a0[2]=(short)f2bf(x0.z); a0[3]=(short)f2bf(x0.w);
      a0[4]=(short)f2bf(x1.x); a0[5]=(short)f2bf(x1.y); a0[6]=(short)f2bf(x1.z); a0[7]=(short)f2bf(x1.w);
      a1[0]=(short)f2bf(y0.x); a1[1]=(short)f2bf(y0.y); a1[2]=(short)f2bf(y0.z); a1[3]=(short)f2bf(y0.w);
      a1[4]=(short)f2bf(y1.x); a1[5]=(short)f2bf(y1.y); a1[6]=(short)f2bf(y1.z); a1[7]=(short)f2bf(y1.w);
      acc0 = MF(a0, bv, acc0);
      acc1 = MF(a1, bv, acc1);
    }
    #pragma unroll
    for (int r = 0; r < 4; ++r){
      int b0 = lh*4 + r, b1 = 16 + b0;
      part[(size_t)(kc*32 + b0)*1024 + j] = acc0[r];
      part[(size_t)(kc*32 + b1)*1024 + j] = acc1[r];
    }
  }
}

// ============ StageD: gemb | initv3r ============
// grid 384 = 256 gemb + 128 initv3r
__global__ __launch_bounds__(256) void k_stageD(const u16* __restrict__ embbf,
    const u16* __restrict__ WIHE, const float* __restrict__ part,
    const float* __restrict__ bh, const float* __restrict__ bc,
    u16* __restrict__ gemb, u16* __restrict__ h_bf, float* __restrict__ c){
  __shared__ u16 A[64*264];
  int blk = blockIdx.x, tid = threadIdx.x;
  if (blk < 256){
    int m0 = (blk >> 3)*64, n0 = (blk & 7)*256;
    int wv = tid>>6, lane = tid&63, lr = lane&15, lh = lane>>4;
    {
      int row = tid>>2, seg = tid&3;
      const u16* src = embbf + (size_t)(m0 + row)*256 + seg*64;
      #pragma unroll
      for (int i = 0; i < 8; i++)
        *(bf16x8*)&A[row*264 + seg*64 + i*8] = *(const bf16x8*)(src + i*8);
    }
    __syncthreads();
    f32x4 acc[4][4];
    #pragma unroll
    for (int mt = 0; mt < 4; mt++)
      #pragma unroll
      for (int nt = 0; nt < 4; nt++) acc[mt][nt] = (f32x4){0,0,0,0};
    #pragma unroll
    for (int ki = 0; ki < 8; ki++){
      bf16x8 av[4];
      #pragma unroll
      for (int mt = 0; mt < 4; mt++)
        av[mt] = *(const bf16x8*)&A[(mt*16 + lr)*264 + ki*32 + lh*8];
      #pragma unroll
      for (int nt = 0; nt < 4; nt++){
        bf16x8 bv = *(const bf16x8*)&WIHE[(size_t)(n0 + wv*64 + nt*16 + lr)*256 + ki*32 + lh*8];
        #pragma unroll
        for (int mt = 0; mt < 4; mt++) acc[mt][nt] = MF(av[mt], bv, acc[mt][nt]);
      }
    }
    #pragma unroll
    for (int nt = 0; nt < 4; nt++){
      int n = n0 + wv*64 + nt*16 + lr;
      #pragma unroll
      for (int mt = 0; mt < 4; mt++)
        #pragma unroll
        for (int r = 0; r < 4; r++)
          gemb[(size_t)(m0 + mt*16 + lh*4 + r)*2048 + n] = f2bf(acc[mt][nt][r]);
    }
  } else {
    int idx = (blk - 256)*256 + tid;
    int b = idx >> 10, j = idx & 1023;
    float s = part[(size_t)b*1024 + j] + part[(size_t)(32+b)*1024 + j]
            + part[(size_t)(64+b)*1024 + j] + part[(size_t)(96+b)*1024 + j];
    if (j < 512) h_bf[(size_t)b*512 + j] = f2bf(s + bh[j]);
    else         c[(size_t)b*512 + (j-512)] = s + bc[j-512];
  }
}

// ============ kAB: fused [kA: pA rows 512..4607 + preds] and [kB1: att2 local + score partials] ============
__global__ __launch_bounds__(256) void kAB(const u16* __restrict__ h, const u16* __restrict__ WAP,
    float* __restrict__ pA, const u16* __restrict__ att1T,
    const float* __restrict__ bdec, const float* __restrict__ wfull,
    float* __restrict__ scp, const float* __restrict__ bfc, const float* __restrict__ bstop,
    const int* __restrict__ len, float* __restrict__ out, int t){
  int blk = blockIdx.x, tid = threadIdx.x;
  if (t == 64 && blk != 64) return;      // final call: preds block only
  if (blk < 65){
    __shared__ u16 HL[32*520];
    int wv = tid>>6, lane = tid&63, lr = lane&15, lh = lane>>4;
    for (int i = tid; i < 4096; i += 256){
      unsigned long long v = ((const unsigned long long*)h)[i];
      int row = i >> 7, col = (i & 127)*4;
      *(unsigned long long*)&HL[row*520 + col] = v;
    }
    __syncthreads();
    int j0 = 512 + blk*64 + wv*16;
    f32x4 acc0 = {0,0,0,0}, acc1 = {0,0,0,0};
    #pragma unroll 4
    for (int ki = 0; ki < 16; ++ki){
      bf16x8 bv = *(const bf16x8*)&WAP[(size_t)(j0+lr)*512 + ki*32 + lh*8];
      bf16x8 a0 = *(const bf16x8*)&HL[lr*520 + ki*32 + lh*8];
      bf16x8 a1 = *(const bf16x8*)&HL[(16+lr)*520 + ki*32 + lh*8];
      acc0 = MF(a0, bv, acc0);
      acc1 = MF(a1, bv, acc1);
    }
    int j = j0 + lr;
    if (j < 4608){
      #pragma unroll
      for (int r = 0; r < 4; ++r){
        pA[(size_t)(lh*4+r)*4608 + j]    = acc0[r];
        pA[(size_t)(lh*4+r+16)*4608 + j] = acc1[r];
      }
    } else if (j < 4611 && t > 0){
      int jj = j - 4608, tm1 = t - 1;
      #pragma unroll
      for (int r = 0; r < 4; ++r){
        #pragma unroll
        for (int hb = 0; hb < 2; ++hb){
          int b0 = lh*4 + r + hb*16;
          float val = hb ? acc1[r] : acc0[r];
          bool mk = tm1 < len[b0];
          if (jj < 2) out[O_PRED + ((size_t)b0*64 + tm1)*2 + jj] = mk ? val + bfc[jj] : 0.f;
          else        out[O_STOP + (size_t)b0*64 + tm1] =
                        mk ? 1.f/(1.f + expf(-(val + bstop[0]))) : 0.f;
        }
      }
    }
  } else {
    int kb = blk - 65, b = kb >> 3, ac = kb & 7;
    if (t >= len[b]) return;
    __shared__ u16 hL[512];
    __shared__ float a2s[64], wfs[64];
    if (tid < 128)
      ((unsigned long long*)hL)[tid] = ((const unsigned long long*)(h + (size_t)b*512))[tid];
    if (tid < 64) wfs[tid] = wfull[ac*64 + tid];
    __syncthreads();
    {
      int a = tid >> 2, q = tid & 3;
      const u16* wrow = WAP + (size_t)(ac*64 + a)*512 + q*128;
      const u16* hrow = hL + q*128;
      float acc = 0.f;
      #pragma unroll
      for (int i = 0; i < 16; ++i){
        bf16x8 wv8 = *(const bf16x8*)(wrow + i*8);
        bf16x8 hv8 = *(const bf16x8*)(hrow + i*8);
        #pragma unroll
        for (int e = 0; e < 8; ++e) acc += bf2f((u16)hv8[e]) * bf2f((u16)wv8[e]);
      }
      acc += __shfl_xor(acc, 1);
      acc += __shfl_xor(acc, 2);
      if (q == 0) a2s[a] = acc + bdec[ac*64 + a];
    }
    __syncthreads();
    int p = tid;
    if (p < 196){
      const u16* col = att1T + ((size_t)b*512 + ac*64)*208 + p;
      float acc = 0.f;
      #pragma unroll 8
      for (int a = 0; a < 64; ++a)
        acc += fmaxf(bf2f(col[(size_t)a*208]) + a2s[a], 0.f) * wfs[a];
      scp[(size_t)(b*8 + ac)*200 + p] = acc;
    }
  }
}

// ============ kB2: softmax + awe + gate -> xa ; alphas ============
__global__ __launch_bounds__(256) void kB2(const float* __restrict__ scp,
    const float* __restrict__ pA, const u16* __restrict__ encbf,
    const float* __restrict__ bfull, const float* __restrict__ bfb,
    u16* __restrict__ xa, const int* __restrict__ len, float* __restrict__ out, int t){
  int b = blockIdx.x >> 3, dc = blockIdx.x & 7;
  int tid = threadIdx.x, wv = tid>>6, lane = tid&63;
  if (t >= len[b]){
    if (dc == 0 && tid < 196) out[O_ALPHA + ((size_t)b*64 + t)*196 + tid] = 0.f;
    return;
  }
  __shared__ float ev[200], redf[4], bcx[2];
  float s = -1e30f;
  if (tid < 196){
    s = bfull[0];
    #pragma unroll
    for (int q = 0; q < 8; ++q) s += scp[(size_t)(b*8 + q)*200 + tid];
  }
  float m = s;
  #pragma unroll
  for (int o = 32; o; o >>= 1) m = fmaxf(m, __shfl_down(m, o));
  if (lane == 0) redf[wv] = m;
  __syncthreads();
  if (tid == 0) bcx[0] = fmaxf(fmaxf(redf[0],redf[1]), fmaxf(redf[2],redf[3]));
  __syncthreads();
  float e = (tid < 196) ? expf(s - bcx[0]) : 0.f;
  if (tid < 200) ev[tid] = (tid < 196) ? e : 0.f;
  float sm = e;
  #pragma unroll
  for (int o = 32; o; o >>= 1) sm += __shfl_down(sm, o);
  __syncthreads();
  if (lane == 0) redf[wv] = sm;
  __syncthreads();
  if (tid == 0) bcx[1] = redf[0]+redf[1]+redf[2]+redf[3];
  __syncthreads();
  float ssum = bcx[1];
  int d = dc*256 + tid;
  const u16* ep = encbf + (size_t)(b*196)*ENCD + d;
  float q[8];
  #pragma unroll
  for (int j = 0; j < 8; ++j) q[j] = 0.f;
  #pragma unroll 2
  for (int p = 0; p < 192; p += 8){
    #pragma unroll
    for (int j = 0; j < 8; ++j)
      q[j] += ev[p+j]*bf2f(ep[(size_t)(p+j)*ENCD]);
  }
  #pragma unroll
  for (int j = 0; j < 4; ++j)
    q[j] += ev[192+j]*bf2f(ep[(size_t)(192+j)*ENCD]);
  float awe = (((q[0]+q[1])+(q[2]+q[3])) + ((q[4]+q[5])+(q[6]+q[7]))) / ssum;
  float gp = pA[(size_t)b*4608 + 512 + d] + bfb[d];
  float gate = 1.f/(1.f + expf(-gp));
  xa[(size_t)b*2048 + d] = f2bf(gate * awe);
  if (dc == 0 && tid < 196) out[O_ALPHA + ((size_t)b*64 + t)*196 + tid] = ev[tid]/ssum;
}

// ============ kC: gates GEMM (8-wave K-split) + LSTM fused ============
__global__ __launch_bounds__(512) void kC(const u16* __restrict__ xa,
    const u16* __restrict__ hc, u16* __restrict__ hn, float* __restrict__ c,
    const u16* __restrict__ WIH2, const float* __restrict__ pA,
    const float* __restrict__ bcomb, const u16* __restrict__ gemb,
    const int* __restrict__ len, int t){
  int tid = threadIdx.x, wv = tid>>6, lane = tid&63, lr = lane&15, lh = lane>>4;
  int jp0 = blockIdx.x*16;
  __shared__ float red[8*512];
  f32x4 acc0 = {0,0,0,0}, acc1 = {0,0,0,0};
  #pragma unroll
  for (int ks = 0; ks < 8; ++ks){
    int k = wv*256 + ks*32;
    bf16x8 a0 = *(const bf16x8*)&xa[(size_t)lr*2048 + k + lh*8];
    bf16x8 a1 = *(const bf16x8*)&xa[(size_t)(16+lr)*2048 + k + lh*8];
    bf16x8 bv = *(const bf16x8*)&WIH2[(size_t)(jp0+lr)*2048 + k + lh*8];
    acc0 = MF(a0, bv, acc0);
    acc1 = MF(a1, bv, acc1);
  }
  #pragma unroll
  for (int r = 0; r < 4; ++r){
    red[wv*512 + ((lh*4+r) << 4) + lr]    = acc0[r];
    red[wv*512 + ((16+lh*4+r) << 4) + lr] = acc1[r];
  }
  __syncthreads();
  {
    int b = tid >> 4, jl = tid & 15, e = jl & 3;
    int jp = jp0 + jl, u = jp >> 2;
    float g = 0.f;
    #pragma unroll
    for (int w = 0; w < 8; ++w) g += red[w*512 + tid];
    g += bcomb[jp] + bf2f(gemb[((size_t)b*64 + t)*2048 + jp])
       + pA[(size_t)b*4608 + 2560 + e*512 + u];
    float sv = (e == 2) ? tanhf(g) : 1.f/(1.f + expf(-g));
    float vb = __shfl_xor(sv, 1), vc = __shfl_xor(sv, 2), vd = __shfl_xor(vb, 2);
    float i_s = (e==0)?sv:(e==1)?vb:(e==2)?vc:vd;
    float f_s = (e==1)?sv:(e==0)?vb:(e==3)?vc:vd;
    float g_t = (e==2)?sv:(e==3)?vb:(e==0)?vc:vd;
    float o_s = (e==3)?sv:(e==2)?vb:(e==1)?vc:vd;
    float cold = c[(size_t)b*512 + u];
    float hold = bf2f(hc[(size_t)b*512 + u]);
    bool mk = t < len[b];
    float cn = mk ? (f_s*cold + i_s*g_t) : cold;
    float hv = mk ? (o_s * tanhf(cn)) : hold;
    if (e == 0){
      c[(size_t)b*512 + u] = cn;
      hn[(size_t)b*512 + u] = f2bf(hv);
    }
  }
}

// ================= host launcher =================
extern "C" void kernel_launch(void* const* d_in, const int* in_sizes, int n_in,
                              void* d_out, int out_size, void* d_ws, size_t ws_size,
                              hipStream_t stream){
  (void)in_sizes; (void)n_in; (void)out_size; (void)ws_size;
  const float* enc_out   = (const float*)d_in[0];
  const float* imgs      = (const float*)d_in[1];
  const int*   seq       = (const int*)d_in[2];
  const float* seqoff    = (const float*)d_in[3];
  const int*   caplen    = (const int*)d_in[4];
  const float* W_pe      = (const float*)d_in[5];
  const float* b_pe      = (const float*)d_in[6];
  const float* W_enc_att = (const float*)d_in[7];
  const float* b_enc_att = (const float*)d_in[8];
  const float* W_dec_att = (const float*)d_in[9];
  const float* b_dec_att = (const float*)d_in[10];
  const float* w_full    = (const float*)d_in[11];
  const float* b_full    = (const float*)d_in[12];
  const float* W_init_h  = (const float*)d_in[13];
  const float* b_init_h  = (const float*)d_in[14];
  const float* W_init_c  = (const float*)d_in[15];
  const float* b_init_c  = (const float*)d_in[16];
  const float* W_fb      = (const float*)d_in[17];
  const float* b_fb      = (const float*)d_in[18];
  const float* W_ih      = (const float*)d_in[19];
  const float* b_ih      = (const float*)d_in[20];
  const float* W_hh      = (const float*)d_in[21];
  const float* b_hh      = (const float*)d_in[22];
  const float* W_fc      = (const float*)d_in[23];
  const float* b_fc      = (const float*)d_in[24];
  const float* W_stop    = (const float*)d_in[25];
  const float* b_stop    = (const float*)d_in[26];

  float* out = (float*)d_out;
  float* ws  = (float*)d_ws;
  int*   wsi = (int*)d_ws;
  u16*   us  = (u16*)d_ws;

  u16* H[2] = { us + US_H0, us + US_H1 };

  k_prep<<<1, 64, 0, stream>>>(caplen, wsi + WS_SORT, wsi + WS_LEN, out);
  k_stageA<<<9872, 256, 0, stream>>>(enc_out, imgs, seq, W_pe, W_enc_att, seqoff,
                                     wsi + WS_SORT,
                                     us + US_ENC, ws + WS_ENCM, us + US_PATCH,
                                     us + US_WPEB, us + US_WEA, out);
  k_stageB<<<520, 256, 0, stream>>>(us + US_PATCH, us + US_WPEB, b_pe,
                                    us + US_ENC, us + US_WEA, b_enc_att,
                                    us + US_EMBBF, ws + WS_EMB0, us + US_ATT1T);
  k_stageC<<<6792, 256, 0, stream>>>(W_ih, W_hh, W_dec_att, W_fb, W_fc, W_stop,
                                     b_ih, b_hh,
                                     ws + WS_ENCM, ws + WS_EMB0, W_init_h, W_init_c,
                                     us + US_WIH2, us + US_WIHE, us + US_WAP,
                                     ws + WS_BCOMB, ws + WS_PA);
  k_stageD<<<384, 256, 0, stream>>>(us + US_EMBBF, us + US_WIHE, ws + WS_PA,
                                    b_init_h, b_init_c,
                                    us + US_GEMB, H[0], ws + WS_C);

  for (int t = 0; t < Tn; ++t){
    kAB<<<321, 256, 0, stream>>>(H[t & 1], us + US_WAP, ws + WS_PA, us + US_ATT1T,
                                 b_dec_att, w_full, ws + WS_SCP, b_fc, b_stop,
                                 wsi + WS_LEN, out, t);
    kB2<<<256, 256, 0, stream>>>(ws + WS_SCP, ws + WS_PA, us + US_ENC, b_full, b_fb,
                                 us + US_XA, wsi + WS_LEN, out, t);
    kC<<<128, 512, 0, stream>>>(us + US_XA, H[t & 1], H[(t + 1) & 1], ws + WS_C,
                                us + US_WIH2, ws + WS_PA, ws + WS_BCOMB, us + US_GEMB,
                                wsi + WS_LEN, t);
  }
  kAB<<<321, 256, 0, stream>>>(H[0], us + US_WAP, ws + WS_PA, us + US_ATT1T,
                               b_dec_att, w_full, ws + WS_SCP, b_fc, b_stop,
                               wsi + WS_LEN, out, 64);
}

// Round 16
// 1833.849 us; speedup vs baseline: 1.3998x; 1.0385x over previous
//
#include <hip/hip_runtime.h>

// ---------------- problem constants ----------------
#define Bn 32
#define Tn 64
#define Pn 196
#define ENCD 2048
#define DECD 512
#define XDIM 2304

typedef unsigned short u16;
typedef __attribute__((ext_vector_type(8))) short bf16x8;
typedef __attribute__((ext_vector_type(4))) float f32x4;

#define MF(a,b,c) __builtin_amdgcn_mfma_f32_16x16x32_bf16(a,b,c,0,0,0)

static __device__ __forceinline__ u16 f2bf(float f){
  unsigned int u = __float_as_uint(f);
  unsigned int r = u + 0x7FFFu + ((u >> 16) & 1u);
  return (u16)(r >> 16);
}
static __device__ __forceinline__ float bf2f(u16 u){
  return __uint_as_float(((unsigned int)u) << 16);
}

// ---------------- output offsets (floats) ----------------
#define O_PRED   0
#define O_STOP   4096
#define O_SEQOFF 6144
#define O_LEN    10240
#define O_ALPHA  10272
#define O_SORT   411680

// ---------------- ws: f32/int region (f32 indices) ----------------
#define WS_SORT    0        // int[32]
#define WS_LEN     32       // int[32]
#define WS_C       64       // f32 [32][512]
#define WS_PA      16448    // f32 [32][4608] (also init partials [4][32][1024] pre-loop)
#define WS_SCP     163904   // f32 [32][8][200] score partials
#define WS_ENCM    215104   // f32 [32][2048]
#define WS_EMB0    280640   // f32 [32][256]
#define WS_BCOMB   288832   // f32 [2048]
// ---------------- ws: u16 region (absolute u16 indices from (u16*)d_ws) ----------------
#define US_H0      800000                 // [32][512]
#define US_H1      816384                 // [32][512]
#define US_XA      832768                 // [32][2048]
#define US_EMBBF   898304                 // [32][64][256]
#define US_ATT1T   1422592                // [32][512][208] transposed att1
#define US_ENC     4830464                // [6272][2048] sorted row-major
#define US_WAP     17675520               // [4672][512] Wdec|Wfb|Whh|Wfc(2)|Wstop|pad
#define US_WIHE    20067584               // [2048][256]  jp-interleaved
#define US_WIH2    20591872               // [2048][2048] jp-interleaved (StageC; clobbers PATCH)
#define US_GEMB    24786176               // [32*64][2048] (StageD; clobbers PATCH tail/WPEB/WEA)
#define US_PATCH   20591872               // [2048][3072] ALIAS (StageA write, StageB read)
#define US_WPEB    26883328               // [256][3072] bf16 W_pe (StageA write, StageB read)
#define US_WEA     27931904               // [512][2048] bf16 W_enc_att (StageA write, StageB read)

// ============ prep: stable descending sort ============
__global__ void k_prep(const int* __restrict__ caplen, int* __restrict__ ws_sort,
                       int* __restrict__ ws_len, float* __restrict__ out){
  __shared__ int len[32];
  int i = threadIdx.x;
  if (i < 32) len[i] = caplen[i];
  __syncthreads();
  if (i < 32){
    int li = len[i], r = 0;
    for (int j = 0; j < 32; j++){
      int lj = len[j];
      r += (lj > li) || (lj == li && j < i);
    }
    ws_sort[r] = i;
    ws_len[r]  = li;
    out[O_LEN + r]  = (float)li;
    out[O_SORT + r] = (float)i;
  }
}

// ============ StageA: encbf | encmean(fp32) | patch | wpeb | wea | seqoff ============
__global__ __launch_bounds__(256) void k_stageA(const float* __restrict__ enc,
    const float* __restrict__ imgs, const int* __restrict__ seq,
    const float* __restrict__ W_pe, const float* __restrict__ Wea,
    const float* __restrict__ seqoff, const int* __restrict__ srt,
    u16* __restrict__ encbf, float* __restrict__ encm, u16* __restrict__ patches,
    u16* __restrict__ wpeb, u16* __restrict__ wead, float* __restrict__ out){
  int blk = blockIdx.x, tid = threadIdx.x;
  if (blk < 6272){
    int m = blk;
    int b = m / 196, p = m - b*196;
    const float* src = enc + ((size_t)srt[b]*196 + p)*ENCD;
    u16* d = encbf + (size_t)m*ENCD;
    int i = tid*8;
    float4 v0 = *(const float4*)(src + i);
    float4 v1 = *(const float4*)(src + i + 4);
    bf16x8 s;
    s[0]=(short)f2bf(v0.x); s[1]=(short)f2bf(v0.y); s[2]=(short)f2bf(v0.z); s[3]=(short)f2bf(v0.w);
    s[4]=(short)f2bf(v1.x); s[5]=(short)f2bf(v1.y); s[6]=(short)f2bf(v1.z); s[7]=(short)f2bf(v1.w);
    *(bf16x8*)(d + i) = s;
  } else if (blk < 6528){
    int r = blk - 6272;
    int b = r >> 3, dc = r & 7;
    int d = dc*256 + tid;
    const float* ep = enc + ((size_t)srt[b]*196)*ENCD + d;
    float s = 0.f;
    #pragma unroll 4
    for (int p = 0; p < Pn; p++) s += ep[(size_t)p*ENCD];
    encm[b*ENCD + d] = s * (1.f/196.f);
  } else if (blk < 8576){
    int r = blk - 6528;
    int b = r>>6, t = r&63;
    int sb = srt[b];
    int x0 = seq[(sb*64+t)*2 + 0], y0 = seq[(sb*64+t)*2 + 1];
    const float* img = imgs + (size_t)sb*3*512*512;
    u16* dst = patches + (size_t)(b*64+t)*3072;
    for (int idx = tid; idx < 3072; idx += 256){
      int c = idx>>10, rem = idx&1023, i = rem>>5, j = rem&31;
      int yy = y0 + i - 24, xx = x0 + j - 24;
      float v = 0.f;
      if ((unsigned)yy < 512u && (unsigned)xx < 512u) v = img[((size_t)c*512 + yy)*512 + xx];
      dst[idx] = f2bf(v);
    }
  } else if (blk < 9344){
    int i = ((blk - 8576)*256 + tid)*4;
    float4 v = *(const float4*)(W_pe + i);
    wpeb[i+0] = f2bf(v.x); wpeb[i+1] = f2bf(v.y);
    wpeb[i+2] = f2bf(v.z); wpeb[i+3] = f2bf(v.w);
  } else if (blk < 9856){
    int r = blk - 9344;
    for (int i = tid; i < 2048; i += 256)
      wead[(size_t)r*2048 + i] = f2bf(Wea[(size_t)r*2048 + i]);
  } else {
    int idx = (blk - 9856)*256 + tid;
    int b = idx >> 7, r = idx & 127;
    out[O_SEQOFF + idx] = seqoff[srt[b]*128 + r];
  }
}

// ============ StageB: embedv3 | att1v4 (LDS stride 138: bank-conflict-free) ============
__global__ __launch_bounds__(256) void k_stageB(const u16* __restrict__ patches,
    const u16* __restrict__ wpeb, const float* __restrict__ b_pe,
    const u16* __restrict__ encbf, const u16* __restrict__ wead,
    const float* __restrict__ bea,
    u16* __restrict__ embbf, float* __restrict__ emb0, u16* __restrict__ att1T){
  __shared__ u16 A[64*138];
  int blk = blockIdx.x, tid = threadIdx.x;
  int wv = tid>>6, lane = tid&63, lr = lane&15, lh = lane>>4;
  if (blk < 128){
    int mb = blk >> 2, nb = blk & 3;
    int m0 = mb*64;
    f32x4 acc[4];
    #pragma unroll
    for (int mt = 0; mt < 4; mt++) acc[mt] = (f32x4){0,0,0,0};
    for (int kc = 0; kc < 24; kc++){
      __syncthreads();
      {
        int row = tid>>2, seg = tid&3;
        const u16* src = patches + (size_t)(m0 + row)*3072 + kc*128 + seg*32;
        #pragma unroll
        for (int i = 0; i < 4; i++)
          *(bf16x8*)&A[row*138 + seg*32 + i*8] = *(const bf16x8*)(src + i*8);
      }
      __syncthreads();
      #pragma unroll
      for (int ki = 0; ki < 4; ki++){
        bf16x8 bv = *(const bf16x8*)&wpeb[(size_t)(nb*64 + wv*16 + lr)*3072 + kc*128 + ki*32 + lh*8];
        #pragma unroll
        for (int mt = 0; mt < 4; mt++){
          bf16x8 av = *(const bf16x8*)&A[(mt*16 + lr)*138 + ki*32 + lh*8];
          acc[mt] = MF(av, bv, acc[mt]);
        }
      }
    }
    int n = nb*64 + wv*16 + lr;
    float bias = b_pe[n];
    #pragma unroll
    for (int mt = 0; mt < 4; mt++){
      #pragma unroll
      for (int r = 0; r < 4; r++){
        int t = mt*16 + lh*4 + r;
        float val = acc[mt][r] + bias;
        embbf[(size_t)(m0 + t)*256 + n] = f2bf(val);
        if (t == 0) emb0[mb*256 + n] = val;
      }
    }
  } else {
    int ab = blk - 128;
    int mb = ab >> 2, nb = ab & 3;
    int m0 = mb*64;
    f32x4 acc[4][2];
    #pragma unroll
    for (int mt = 0; mt < 4; mt++){ acc[mt][0] = (f32x4){0,0,0,0}; acc[mt][1] = (f32x4){0,0,0,0}; }
    for (int kc = 0; kc < 16; kc++){
      __syncthreads();
      {
        int row = tid>>2, seg = tid&3;
        const u16* src = encbf + (size_t)(m0 + row)*2048 + kc*128 + seg*32;
        #pragma unroll
        for (int i = 0; i < 4; i++)
          *(bf16x8*)&A[row*138 + seg*32 + i*8] = *(const bf16x8*)(src + i*8);
      }
      __syncthreads();
      #pragma unroll
      for (int ki = 0; ki < 4; ki++){
        bf16x8 av[4];
        #pragma unroll
        for (int mt = 0; mt < 4; mt++)
          av[mt] = *(const bf16x8*)&A[(mt*16 + lr)*138 + ki*32 + lh*8];
        #pragma unroll
        for (int nt = 0; nt < 2; nt++){
          const u16* wp = wead + (size_t)(nb*128 + wv*32 + nt*16 + lr)*2048 + kc*128 + ki*32 + lh*8;
          bf16x8 bv = *(const bf16x8*)wp;
          #pragma unroll
          for (int mt = 0; mt < 4; mt++) acc[mt][nt] = MF(av[mt], bv, acc[mt][nt]);
        }
      }
    }
    #pragma unroll
    for (int nt = 0; nt < 2; nt++){
      int n = nb*128 + wv*32 + nt*16 + lr;
      float bias = bea[n];
      #pragma unroll
      for (int mt = 0; mt < 4; mt++){
        #pragma unroll
        for (int r = 0; r < 4; r++){
          int m = m0 + mt*16 + lh*4 + r;
          int bb = m / 196, pp = m - bb*196;
          att1T[((size_t)bb*512 + n)*208 + pp] = f2bf(acc[mt][nt][r] + bias);
        }
      }
    }
  }
}

// ============ StageC: W_ih->WIH2/WIHE | WAP | bcomb | initv3 ============
__global__ __launch_bounds__(256) void k_stageC(const float* __restrict__ Wih,
    const float* __restrict__ Whh, const float* __restrict__ Wdec,
    const float* __restrict__ Wfb, const float* __restrict__ Wfc,
    const float* __restrict__ Wstop, const float* __restrict__ bih,
    const float* __restrict__ bhh,
    const float* __restrict__ encm, const float* __restrict__ emb0,
    const float* __restrict__ Wh, const float* __restrict__ Wc,
    u16* __restrict__ WIH2, u16* __restrict__ WIHE, u16* __restrict__ WAP,
    float* __restrict__ bcomb, float* __restrict__ part){
  int blk = blockIdx.x, tid = threadIdx.x;
  if (blk < 2048){
    int r = blk, jp = (r & 511)*4 + (r >> 9);
    for (int i = tid; i < 2304; i += 256){
      u16 v = f2bf(Wih[(size_t)r*2304 + i]);
      if (i < 2048) WIH2[(size_t)jp*2048 + i] = v;
      else          WIHE[(size_t)jp*256 + (i - 2048)] = v;
    }
  } else if (blk < 6720){
    int j = blk - 2048;
    const float* src;
    if (j < 512)        src = Wdec + (size_t)j*512;
    else if (j < 2560)  src = Wfb + (size_t)(j-512)*512;
    else if (j < 4608)  src = Whh + (size_t)(j-2560)*512;
    else if (j == 4608) src = Wfc;
    else if (j == 4609) src = Wfc + 512;
    else if (j == 4610) src = Wstop;
    else src = 0;
    for (int i = tid; i < 512; i += 256)
      WAP[(size_t)j*512 + i] = src ? f2bf(src[i]) : (u16)0;
  } else if (blk < 6728){
    int jp = (blk - 6720)*256 + tid;
    int r = (jp & 3)*512 + (jp >> 2);
    bcomb[jp] = bih[r] + bhh[r];
  } else {
    int ib = blk - 6728;
    int kc = ib >> 4, jb = ib & 15;
    int wv = tid>>6, lane = tid&63, lr = lane&15, lh = lane>>4;
    int j = jb*64 + wv*16 + lr;
    const float* wbase = (j < 512) ? (Wh + (size_t)j*XDIM) : (Wc + (size_t)(j-512)*XDIM);
    f32x4 acc0 = {0,0,0,0}, acc1 = {0,0,0,0};
    #pragma unroll 2
    for (int kk = 0; kk < 576; kk += 32){
      int k = kc*576 + kk + lh*8;
      float4 w0 = *(const float4*)(wbase + k);
      float4 w1 = *(const float4*)(wbase + k + 4);
      bf16x8 bv;
      bv[0]=(short)f2bf(w0.x); bv[1]=(short)f2bf(w0.y); bv[2]=(short)f2bf(w0.z); bv[3]=(short)f2bf(w0.w);
      bv[4]=(short)f2bf(w1.x); bv[5]=(short)f2bf(w1.y); bv[6]=(short)f2bf(w1.z); bv[7]=(short)f2bf(w1.w);
      float4 x0, x1, y0, y1;
      if (k < 2048){
        x0 = *(const float4*)(encm + (size_t)lr*2048 + k);
        x1 = *(const float4*)(encm + (size_t)lr*2048 + k + 4);
        y0 = *(const float4*)(encm + (size_t)(16+lr)*2048 + k);
        y1 = *(const float4*)(encm + (size_t)(16+lr)*2048 + k + 4);
      } else {
        int ke = k - 2048;
        x0 = *(const float4*)(emb0 + (size_t)lr*256 + ke);
        x1 = *(const float4*)(emb0 + (size_t)lr*256 + ke + 4);
        y0 = *(const float4*)(emb0 + (size_t)(16+lr)*256 + ke);
        y1 = *(const float4*)(emb0 + (size_t)(16+lr)*256 + ke + 4);
      }
      bf16x8 a0, a1;
      a0[0]=(short)f2bf(x0.x); a0[1]=(short)f2bf(x0.y); a0[2]=(short)f2bf(x0.z); a0[3]=(short)f2bf(x0.w);
      a0[4]=(short)f2bf(x1.x); a0[5]=(short)f2bf(x1.y); a0[6]=(short)f2bf(x1.z); a0[7]=(short)f2bf(x1.w);
      a1[0]=(short)f2bf(y0.x); a1[1]=(short)f2bf(y0.y); a1[2]=(short)f2bf(y0.z); a1[3]=(short)f2bf(y0.w);
      a1[4]=(short)f2bf(y1.x); a1[5]=(short)f2bf(y1.y); a1[6]=(short)f2bf(y1.z); a1[7]=(short)f2bf(y1.w);
      acc0 = MF(a0, bv, acc0);
      acc1 = MF(a1, bv, acc1);
    }
    #pragma unroll
    for (int r = 0; r < 4; ++r){
      int b0 = lh*4 + r, b1 = 16 + b0;
      part[(size_t)(kc*32 + b0)*1024 + j] = acc0[r];
      part[(size_t)(kc*32 + b1)*1024 + j] = acc1[r];
    }
  }
}

// ============ StageD: gemb | initv3r (gemb LDS stride 266) ============
__global__ __launch_bounds__(256) void k_stageD(const u16* __restrict__ embbf,
    const u16* __restrict__ WIHE, const float* __restrict__ part,
    const float* __restrict__ bh, const float* __restrict__ bc,
    u16* __restrict__ gemb, u16* __restrict__ h_bf, float* __restrict__ c){
  __shared__ u16 A[64*266];
  int blk = blockIdx.x, tid = threadIdx.x;
  if (blk < 256){
    int m0 = (blk >> 3)*64, n0 = (blk & 7)*256;
    int wv = tid>>6, lane = tid&63, lr = lane&15, lh = lane>>4;
    {
      int row = tid>>2, seg = tid&3;
      const u16* src = embbf + (size_t)(m0 + row)*256 + seg*64;
      #pragma unroll
      for (int i = 0; i < 8; i++)
        *(bf16x8*)&A[row*266 + seg*64 + i*8] = *(const bf16x8*)(src + i*8);
    }
    __syncthreads();
    f32x4 acc[4][4];
    #pragma unroll
    for (int mt = 0; mt < 4; mt++)
      #pragma unroll
      for (int nt = 0; nt < 4; nt++) acc[mt][nt] = (f32x4){0,0,0,0};
    #pragma unroll
    for (int ki = 0; ki < 8; ki++){
      bf16x8 av[4];
      #pragma unroll
      for (int mt = 0; mt < 4; mt++)
        av[mt] = *(const bf16x8*)&A[(mt*16 + lr)*266 + ki*32 + lh*8];
      #pragma unroll
      for (int nt = 0; nt < 4; nt++){
        bf16x8 bv = *(const bf16x8*)&WIHE[(size_t)(n0 + wv*64 + nt*16 + lr)*256 + ki*32 + lh*8];
        #pragma unroll
        for (int mt = 0; mt < 4; mt++) acc[mt][nt] = MF(av[mt], bv, acc[mt][nt]);
      }
    }
    #pragma unroll
    for (int nt = 0; nt < 4; nt++){
      int n = n0 + wv*64 + nt*16 + lr;
      #pragma unroll
      for (int mt = 0; mt < 4; mt++)
        #pragma unroll
        for (int r = 0; r < 4; r++)
          gemb[(size_t)(m0 + mt*16 + lh*4 + r)*2048 + n] = f2bf(acc[mt][nt][r]);
    }
  } else {
    int idx = (blk - 256)*256 + tid;
    int b = idx >> 10, j = idx & 1023;
    float s = part[(size_t)b*1024 + j] + part[(size_t)(32+b)*1024 + j]
            + part[(size_t)(64+b)*1024 + j] + part[(size_t)(96+b)*1024 + j];
    if (j < 512) h_bf[(size_t)b*512 + j] = f2bf(s + bh[j]);
    else         c[(size_t)b*512 + (j-512)] = s + bc[j-512];
  }
}

// ============ kAB: fused [kA: pA rows 512..4607 + preds] and [kB1] (HL stride 522) ============
__global__ __launch_bounds__(256) void kAB(const u16* __restrict__ h, const u16* __restrict__ WAP,
    float* __restrict__ pA, const u16* __restrict__ att1T,
    const float* __restrict__ bdec, const float* __restrict__ wfull,
    float* __restrict__ scp, const float* __restrict__ bfc, const float* __restrict__ bstop,
    const int* __restrict__ len, float* __restrict__ out, int t){
  int blk = blockIdx.x, tid = threadIdx.x;
  if (t == 64 && blk != 64) return;      // final call: preds block only
  if (blk < 65){
    __shared__ u16 HL[32*522];
    int wv = tid>>6, lane = tid&63, lr = lane&15, lh = lane>>4;
    for (int i = tid; i < 4096; i += 256){
      unsigned long long v = ((const unsigned long long*)h)[i];
      int row = i >> 7, col = (i & 127)*4;
      *(unsigned long long*)&HL[row*522 + col] = v;
    }
    __syncthreads();
    int j0 = 512 + blk*64 + wv*16;
    f32x4 acc0 = {0,0,0,0}, acc1 = {0,0,0,0};
    #pragma unroll 4
    for (int ki = 0; ki < 16; ++ki){
      bf16x8 bv = *(const bf16x8*)&WAP[(size_t)(j0+lr)*512 + ki*32 + lh*8];
      bf16x8 a0 = *(const bf16x8*)&HL[lr*522 + ki*32 + lh*8];
      bf16x8 a1 = *(const bf16x8*)&HL[(16+lr)*522 + ki*32 + lh*8];
      acc0 = MF(a0, bv, acc0);
      acc1 = MF(a1, bv, acc1);
    }
    int j = j0 + lr;
    if (j < 4608){
      #pragma unroll
      for (int r = 0; r < 4; ++r){
        pA[(size_t)(lh*4+r)*4608 + j]    = acc0[r];
        pA[(size_t)(lh*4+r+16)*4608 + j] = acc1[r];
      }
    } else if (j < 4611 && t > 0){
      int jj = j - 4608, tm1 = t - 1;
      #pragma unroll
      for (int r = 0; r < 4; ++r){
        #pragma unroll
        for (int hb = 0; hb < 2; ++hb){
          int b0 = lh*4 + r + hb*16;
          float val = hb ? acc1[r] : acc0[r];
          bool mk = tm1 < len[b0];
          if (jj < 2) out[O_PRED + ((size_t)b0*64 + tm1)*2 + jj] = mk ? val + bfc[jj] : 0.f;
          else        out[O_STOP + (size_t)b0*64 + tm1] =
                        mk ? 1.f/(1.f + expf(-(val + bstop[0]))) : 0.f;
        }
      }
    }
  } else {
    int kb = blk - 65, b = kb >> 3, ac = kb & 7;
    if (t >= len[b]) return;
    __shared__ u16 hL[512];
    __shared__ float a2s[64], wfs[64];
    if (tid < 128)
      ((unsigned long long*)hL)[tid] = ((const unsigned long long*)(h + (size_t)b*512))[tid];
    if (tid < 64) wfs[tid] = wfull[ac*64 + tid];
    __syncthreads();
    {
      int a = tid >> 2, q = tid & 3;
      const u16* wrow = WAP + (size_t)(ac*64 + a)*512 + q*128;
      const u16* hrow = hL + q*128;
      float acc = 0.f;
      #pragma unroll
      for (int i = 0; i < 16; ++i){
        bf16x8 wv8 = *(const bf16x8*)(wrow + i*8);
        bf16x8 hv8 = *(const bf16x8*)(hrow + i*8);
        #pragma unroll
        for (int e = 0; e < 8; ++e) acc += bf2f((u16)hv8[e]) * bf2f((u16)wv8[e]);
      }
      acc += __shfl_xor(acc, 1);
      acc += __shfl_xor(acc, 2);
      if (q == 0) a2s[a] = acc + bdec[ac*64 + a];
    }
    __syncthreads();
    int p = tid;
    if (p < 196){
      const u16* col = att1T + ((size_t)b*512 + ac*64)*208 + p;
      float acc = 0.f;
      #pragma unroll 8
      for (int a = 0; a < 64; ++a)
        acc += fmaxf(bf2f(col[(size_t)a*208]) + a2s[a], 0.f) * wfs[a];
      scp[(size_t)(b*8 + ac)*200 + p] = acc;
    }
  }
}

// ============ kB2: softmax + awe + gate -> xa ; alphas ============
__global__ __launch_bounds__(256) void kB2(const float* __restrict__ scp,
    const float* __restrict__ pA, const u16* __restrict__ encbf,
    const float* __restrict__ bfull, const float* __restrict__ bfb,
    u16* __restrict__ xa, const int* __restrict__ len, float* __restrict__ out, int t){
  int b = blockIdx.x >> 3, dc = blockIdx.x & 7;
  int tid = threadIdx.x, wv = tid>>6, lane = tid&63;
  if (t >= len[b]){
    if (dc == 0 && tid < 196) out[O_ALPHA + ((size_t)b*64 + t)*196 + tid] = 0.f;
    return;
  }
  __shared__ float ev[200], redf[4], bcx[2];
  float s = -1e30f;
  if (tid < 196){
    s = bfull[0];
    #pragma unroll
    for (int q = 0; q < 8; ++q) s += scp[(size_t)(b*8 + q)*200 + tid];
  }
  float m = s;
  #pragma unroll
  for (int o = 32; o; o >>= 1) m = fmaxf(m, __shfl_down(m, o));
  if (lane == 0) redf[wv] = m;
  __syncthreads();
  if (tid == 0) bcx[0] = fmaxf(fmaxf(redf[0],redf[1]), fmaxf(redf[2],redf[3]));
  __syncthreads();
  float e = (tid < 196) ? expf(s - bcx[0]) : 0.f;
  if (tid < 200) ev[tid] = (tid < 196) ? e : 0.f;
  float sm = e;
  #pragma unroll
  for (int o = 32; o; o >>= 1) sm += __shfl_down(sm, o);
  __syncthreads();
  if (lane == 0) redf[wv] = sm;
  __syncthreads();
  if (tid == 0) bcx[1] = redf[0]+redf[1]+redf[2]+redf[3];
  __syncthreads();
  float ssum = bcx[1];
  int d = dc*256 + tid;
  const u16* ep = encbf + (size_t)(b*196)*ENCD + d;
  float q[8];
  #pragma unroll
  for (int j = 0; j < 8; ++j) q[j] = 0.f;
  #pragma unroll 2
  for (int p = 0; p < 192; p += 8){
    #pragma unroll
    for (int j = 0; j < 8; ++j)
      q[j] += ev[p+j]*bf2f(ep[(size_t)(p+j)*ENCD]);
  }
  #pragma unroll
  for (int j = 0; j < 4; ++j)
    q[j] += ev[192+j]*bf2f(ep[(size_t)(192+j)*ENCD]);
  float awe = (((q[0]+q[1])+(q[2]+q[3])) + ((q[4]+q[5])+(q[6]+q[7]))) / ssum;
  float gp = pA[(size_t)b*4608 + 512 + d] + bfb[d];
  float gate = 1.f/(1.f + expf(-gp));
  xa[(size_t)b*2048 + d] = f2bf(gate * awe);
  if (dc == 0 && tid < 196) out[O_ALPHA + ((size_t)b*64 + t)*196 + tid] = ev[tid]/ssum;
}

// ============ kC: gates GEMM (8-wave K-split) + LSTM fused ============
__global__ __launch_bounds__(512) void kC(const u16* __restrict__ xa,
    const u16* __restrict__ hc, u16* __restrict__ hn, float* __restrict__ c,
    const u16* __restrict__ WIH2, const float* __restrict__ pA,
    const float* __restrict__ bcomb, const u16* __restrict__ gemb,
    const int* __restrict__ len, int t){
  int tid = threadIdx.x, wv = tid>>6, lane = tid&63, lr = lane&15, lh = lane>>4;
  int jp0 = blockIdx.x*16;
  __shared__ float red[8*512];
  f32x4 acc0 = {0,0,0,0}, acc1 = {0,0,0,0};
  #pragma unroll
  for (int ks = 0; ks < 8; ++ks){
    int k = wv*256 + ks*32;
    bf16x8 a0 = *(const bf16x8*)&xa[(size_t)lr*2048 + k + lh*8];
    bf16x8 a1 = *(const bf16x8*)&xa[(size_t)(16+lr)*2048 + k + lh*8];
    bf16x8 bv = *(const bf16x8*)&WIH2[(size_t)(jp0+lr)*2048 + k + lh*8];
    acc0 = MF(a0, bv, acc0);
    acc1 = MF(a1, bv, acc1);
  }
  #pragma unroll
  for (int r = 0; r < 4; ++r){
    red[wv*512 + ((lh*4+r) << 4) + lr]    = acc0[r];
    red[wv*512 + ((16+lh*4+r) << 4) + lr] = acc1[r];
  }
  __syncthreads();
  {
    int b = tid >> 4, jl = tid & 15, e = jl & 3;
    int jp = jp0 + jl, u = jp >> 2;
    float g = 0.f;
    #pragma unroll
    for (int w = 0; w < 8; ++w) g += red[w*512 + tid];
    g += bcomb[jp] + bf2f(gemb[((size_t)b*64 + t)*2048 + jp])
       + pA[(size_t)b*4608 + 2560 + e*512 + u];
    float sv = (e == 2) ? tanhf(g) : 1.f/(1.f + expf(-g));
    float vb = __shfl_xor(sv, 1), vc = __shfl_xor(sv, 2), vd = __shfl_xor(vb, 2);
    float i_s = (e==0)?sv:(e==1)?vb:(e==2)?vc:vd;
    float f_s = (e==1)?sv:(e==0)?vb:(e==3)?vc:vd;
    float g_t = (e==2)?sv:(e==3)?vb:(e==0)?vc:vd;
    float o_s = (e==3)?sv:(e==2)?vb:(e==1)?vc:vd;
    float cold = c[(size_t)b*512 + u];
    float hold = bf2f(hc[(size_t)b*512 + u]);
    bool mk = t < len[b];
    float cn = mk ? (f_s*cold + i_s*g_t) : cold;
    float hv = mk ? (o_s * tanhf(cn)) : hold;
    if (e == 0){
      c[(size_t)b*512 + u] = cn;
      hn[(size_t)b*512 + u] = f2bf(hv);
    }
  }
}

// ================= host launcher =================
extern "C" void kernel_launch(void* const* d_in, const int* in_sizes, int n_in,
                              void* d_out, int out_size, void* d_ws, size_t ws_size,
                              hipStream_t stream){
  (void)in_sizes; (void)n_in; (void)out_size; (void)ws_size;
  const float* enc_out   = (const float*)d_in[0];
  const float* imgs      = (const float*)d_in[1];
  const int*   seq       = (const int*)d_in[2];
  const float* seqoff    = (const float*)d_in[3];
  const int*   caplen    = (const int*)d_in[4];
  const float* W_pe      = (const float*)d_in[5];
  const float* b_pe      = (const float*)d_in[6];
  const float* W_enc_att = (const float*)d_in[7];
  const float* b_enc_att = (const float*)d_in[8];
  const float* W_dec_att = (const float*)d_in[9];
  const float* b_dec_att = (const float*)d_in[10];
  const float* w_full    = (const float*)d_in[11];
  const float* b_full    = (const float*)d_in[12];
  const float* W_init_h  = (const float*)d_in[13];
  const float* b_init_h  = (const float*)d_in[14];
  const float* W_init_c  = (const float*)d_in[15];
  const float* b_init_c  = (const float*)d_in[16];
  const float* W_fb      = (const float*)d_in[17];
  const float* b_fb      = (const float*)d_in[18];
  const float* W_ih      = (const float*)d_in[19];
  const float* b_ih      = (const float*)d_in[20];
  const float* W_hh      = (const float*)d_in[21];
  const float* b_hh      = (const float*)d_in[22];
  const float* W_fc      = (const float*)d_in[23];
  const float* b_fc      = (const float*)d_in[24];
  const float* W_stop    = (const float*)d_in[25];
  const float* b_stop    = (const float*)d_in[26];

  float* out = (float*)d_out;
  float* ws  = (float*)d_ws;
  int*   wsi = (int*)d_ws;
  u16*   us  = (u16*)d_ws;

  u16* H[2] = { us + US_H0, us + US_H1 };

  k_prep<<<1, 64, 0, stream>>>(caplen, wsi + WS_SORT, wsi + WS_LEN, out);
  k_stageA<<<9872, 256, 0, stream>>>(enc_out, imgs, seq, W_pe, W_enc_att, seqoff,
                                     wsi + WS_SORT,
                                     us + US_ENC, ws + WS_ENCM, us + US_PATCH,
                                     us + US_WPEB, us + US_WEA, out);
  k_stageB<<<520, 256, 0, stream>>>(us + US_PATCH, us + US_WPEB, b_pe,
                                    us + US_ENC, us + US_WEA, b_enc_att,
                                    us + US_EMBBF, ws + WS_EMB0, us + US_ATT1T);
  k_stageC<<<6792, 256, 0, stream>>>(W_ih, W_hh, W_dec_att, W_fb, W_fc, W_stop,
                                     b_ih, b_hh,
                                     ws + WS_ENCM, ws + WS_EMB0, W_init_h, W_init_c,
                                     us + US_WIH2, us + US_WIHE, us + US_WAP,
                                     ws + WS_BCOMB, ws + WS_PA);
  k_stageD<<<384, 256, 0, stream>>>(us + US_EMBBF, us + US_WIHE, ws + WS_PA,
                                    b_init_h, b_init_c,
                                    us + US_GEMB, H[0], ws + WS_C);

  for (int t = 0; t < Tn; ++t){
    kAB<<<321, 256, 0, stream>>>(H[t & 1], us + US_WAP, ws + WS_PA, us + US_ATT1T,
                                 b_dec_att, w_full, ws + WS_SCP, b_fc, b_stop,
                                 wsi + WS_LEN, out, t);
    kB2<<<256, 256, 0, stream>>>(ws + WS_SCP, ws + WS_PA, us + US_ENC, b_full, b_fb,
                                 us + US_XA, wsi + WS_LEN, out, t);
    kC<<<128, 512, 0, stream>>>(us + US_XA, H[t & 1], H[(t + 1) & 1], ws + WS_C,
                                us + US_WIH2, ws + WS_PA, ws + WS_BCOMB, us + US_GEMB,
                                wsi + WS_LEN, t);
  }
  kAB<<<65, 256, 0, stream>>>(H[0], us + US_WAP, ws + WS_PA, us + US_ATT1T,
                              b_dec_att, w_full, ws + WS_SCP, b_fc, b_stop,
                              wsi + WS_LEN, out, 64);
}